// Round 2
// baseline (9689.574 us; speedup 1.0000x reference)
//
#include <hip/hip_runtime.h>
#include <hip/hip_bf16.h>

#define NNODE   2000
#define NG      8
#define EPG     64000
#define TSTEPS  24
#define HOR     10
#define NSTEP   (HOR-1)
#define PITCH   2048          // per-graph node pitch; row 2047 is the zero row
#define ECAP    98304         // padded CSR capacity (ushorts)
#define TILES   125           // 2000 / 16

// ---- workspace layout (bytes) ----
#define OFF_DESC    0
#define OFF_HA      196608
#define OFF_HB      2293760
#define OFF_YIN     4390912
#define OFF_YB      4456448
#define OFF_KA      4521984
#define OFF_KB      4587520
#define OFF_KC      4653056
#define OFF_S4      4718592
#define OFF_DEG     4784128
#define OFF_CUR     4792320   // cursor during setup; reused as barrier counters in k_ode
#define OFF_ROWP    4800512
#define OFF_DINV    4808960
#define OFF_MODES   4817152
#define OFF_WF      4817408
#define OFF_WFRAG   4868352
// total 4917504 B — identical to the proven footprint (no growth)

#define W0OFF 0
#define B0OFF 64
#define W1OFF 128
#define B1OFF 4224
#define W2OFF 4288
#define B2OFF 8384
#define W3OFF 8448
#define B3OFF 12544
#define W4OFF 12608
#define B4OFF 12672
#define WFTOT 12673

typedef __attribute__((ext_vector_type(8))) short short8;
typedef __attribute__((ext_vector_type(4))) float f32x4;
typedef __attribute__((ext_vector_type(2))) float f32x2;

struct WPtrs { const void* p[10]; };

__device__ inline float tanh_fast(float x) {
    float xc = fminf(fmaxf(x, -15.f), 15.f);
    float e  = __expf(2.f * xc);
    return 1.f - 2.f / (e + 1.f);
}
__device__ inline unsigned short f2bf(float f) {
    unsigned u = __float_as_uint(f);
    u += 0x7fff + ((u >> 16) & 1);
    return (unsigned short)(u >> 16);
}
__device__ inline float bf2f(unsigned short h) {
    return __uint_as_float(((unsigned)h) << 16);
}
__device__ inline int ld_idx(const void* p, long i, int imode) {
    return imode ? (int)((const long long*)p)[i] : ((const int*)p)[i];
}

// unpack one dword (2 bf16 feats) into a register-pair float2 -> feeds v_pk_add_f32
__device__ inline f32x2 unpk(unsigned v) {
    f32x2 r;
    r.x = __uint_as_float(v << 16);
    r.y = __uint_as_float(v & 0xffff0000u);
    return r;
}

// ================= setup kernels =================

__global__ void k_detect(const void* x, const void* eidx, int* modes) {
    int lane = threadIdx.x;
    const unsigned* xw = (const unsigned*)x;
    unsigned w = xw[lane];
    int ex = (w >> 7) & 0xFF;
    unsigned long long m = __ballot(ex >= 100 && ex <= 145);
    const unsigned* ew = (const unsigned*)eidx;
    unsigned long long m2 = __ballot(ew[2*lane + 1] != 0);
    if (lane == 0) {
        modes[0] = (__popcll(m) >= 48) ? 1 : 0;
        modes[1] = (__popcll(m2) == 0) ? 1 : 0;
    }
}

// merged: deg init + desc sentinel fill + h pad-row zeroing
__global__ void k_setup0(int* deg, unsigned* desc32, unsigned* hA32, unsigned* hB32) {
    int n = blockIdx.x * 256 + threadIdx.x;
    if (n < PITCH) deg[n] = (n < NNODE) ? 1 : 0;
    if (n < ECAP / 2) desc32[n] = 0x07FF07FFu;     // sentinel -> zero row 2047
    if (n < 2 * NG * 48 * 32) {
        int b = n / (NG * 48 * 32), r = n % (NG * 48 * 32);
        int g = r / (48 * 32), rr = r % (48 * 32);
        int row = NNODE + rr / 32, fp = rr % 32;
        unsigned* pp = b ? hB32 : hA32;
        pp[(g * PITCH + row) * 32 + fp] = 0;
    }
}

__global__ void k_count(const void* eidx, const int* __restrict__ modes, int* deg) {
    int e = blockIdx.x * 256 + threadIdx.x;
    int imode = modes[1];
    int dst = ld_idx(eidx, (long)EPG + e, imode);
    atomicAdd(&deg[dst], 1);
}

__global__ __launch_bounds__(256) void k_scan(const int* __restrict__ deg, int* rowp,
                                              int* cursor, float* dinv) {
    __shared__ int part[256];
    int t = threadIdx.x, base = t * 8;
    int loc[8]; int s = 0;
    #pragma unroll
    for (int k = 0; k < 8; ++k) {
        int d = deg[base + k];
        int p = (d + 15) & ~15;
        loc[k] = p; s += p;
    }
    part[t] = s; __syncthreads();
    for (int off = 1; off < 256; off <<= 1) {
        int v = (t >= off) ? part[t - off] : 0;
        __syncthreads();
        part[t] += v;
        __syncthreads();
    }
    int run = part[t] - s;
    #pragma unroll
    for (int k = 0; k < 8; ++k) {
        rowp[base + k] = run; cursor[base + k] = run;
        int d = deg[base + k];
        dinv[base + k] = (d > 0) ? rsqrtf((float)d) : 0.f;
        run += loc[k];
    }
    if (t == 255) rowp[PITCH] = part[255];
}

__global__ void k_scatter(const void* eidx, const int* __restrict__ modes,
                          int* cursor, unsigned short* desc) {
    int idx = blockIdx.x * 256 + threadIdx.x;
    if (idx >= EPG + NNODE) return;
    int imode = modes[1];
    int s, d;
    if (idx < EPG) { s = ld_idx(eidx, idx, imode); d = ld_idx(eidx, (long)EPG + idx, imode); }
    else           { s = idx - EPG; d = s; }
    int pos = atomicAdd(&cursor[d], 1);
    desc[pos] = (unsigned short)s;
}

__global__ void k_convert(WPtrs wp, float* wf, const int* __restrict__ modes) {
    int idx = blockIdx.x * 256 + threadIdx.x;
    if (idx >= WFTOT) return;
    int fmode = modes[0];
    const int offs[10]  = {W0OFF,B0OFF,W1OFF,B1OFF,W2OFF,B2OFF,W3OFF,B3OFF,W4OFF,B4OFF};
    const int sizes[10] = {64,64,4096,64,4096,64,4096,64,64,1};
    #pragma unroll
    for (int s = 0; s < 10; ++s) {
        if (idx >= offs[s] && idx < offs[s] + sizes[s]) {
            int j = idx - offs[s];
            wf[idx] = fmode ? __bfloat162float(((const __hip_bfloat16*)wp.p[s])[j])
                            : ((const float*)wp.p[s])[j];
        }
    }
}

__global__ void k_mkfrag(const float* __restrict__ wf, short8* frag) {
    int t = blockIdx.x * 256 + threadIdx.x;
    if (t >= 3072) return;
    int lane = t & 63, half = (t >> 6) & 1, kh = (t >> 7) & 1, nb = (t >> 8) & 3, mat = t >> 10;
    const int woffs[3] = {W1OFF, W2OFF, W3OFF};
    const float* W = wf + woffs[mat];
    int n  = nb * 16 + (lane & 15);
    int k0 = kh * 32 + (lane >> 4) * 8;
    short8 v;
    #pragma unroll
    for (int j = 0; j < 8; ++j) {
        float w = W[(k0 + j) * 64 + n];
        unsigned short h = f2bf(w);
        v[j] = half ? (short)f2bf(w - bf2f(h)) : (short)h;
    }
    frag[t] = v;
}

// also zeroes the barrier counters (relocated into the dead cursor region)
__global__ void k_finalize(const float* __restrict__ dinv, const void* x,
                           const int* __restrict__ modes, unsigned* bars,
                           float* yin, float* yb, float* s4, void* out) {
    int idx = blockIdx.x * 256 + threadIdx.x;
    if (idx < 512) bars[idx] = 0u;
    if (idx >= NG * PITCH) return;
    int g = idx >> 11, local = idx & (PITCH - 1);
    if (local >= NNODE) { yin[idx] = 0.f; yb[idx] = 0.f; s4[idx] = 0.f; return; }
    int cn = g * NNODE + local;
    float y0 = modes[0] ? __bfloat162float(((const __hip_bfloat16*)x)[cn * TSTEPS + (TSTEPS - 1)])
                        : ((const float*)x)[cn * TSTEPS + (TSTEPS - 1)];
    yin[idx] = dinv[local] * y0;
    yb[idx]  = y0;
    if (modes[0]) ((__hip_bfloat16*)out)[cn * HOR] = __float2bfloat16(y0);
    else          ((float*)out)[cn * HOR] = y0;
}

// ---- heavy gather: dwordx4 rows, 32-edge unroll, packed f32x2 accumulators ----
__device__ __forceinline__ void acc8(uint4 v, f32x2& a01, f32x2& a23,
                                     f32x2& a45, f32x2& a67) {
    a01 += unpk(v.x);
    a23 += unpk(v.y);
    a45 += unpk(v.z);
    a67 += unpk(v.w);
}

__device__ __forceinline__ void gather_tile(
        const uint4* __restrict__ hg128, const unsigned short* __restrict__ desc,
        const int* __restrict__ rowp, const float* __restrict__ dinv,
        int tb, int lane, int wv, float* tile, float* dinvt) {
    int fp3 = lane & 7, p8 = lane >> 3;
    #pragma unroll
    for (int r = 0; r < 4; ++r) {
        int m = (wv << 2) + r;
        int local = tb + m;
        int s = rowp[local], e = rowp[local + 1];   // multiples of 16
        f32x2 a01 = {0.f, 0.f}, a23 = {0.f, 0.f}, a45 = {0.f, 0.f}, a67 = {0.f, 0.f};
        int i = s;
        for (; i + 32 <= e; i += 32) {
            unsigned e0 = desc[i + p8];
            unsigned e1 = desc[i + 8 + p8];
            unsigned e2 = desc[i + 16 + p8];
            unsigned e3 = desc[i + 24 + p8];
            uint4 v0 = hg128[(e0 << 3) + fp3];
            uint4 v1 = hg128[(e1 << 3) + fp3];
            uint4 v2 = hg128[(e2 << 3) + fp3];
            uint4 v3 = hg128[(e3 << 3) + fp3];
            acc8(v0, a01, a23, a45, a67);
            acc8(v1, a01, a23, a45, a67);
            acc8(v2, a01, a23, a45, a67);
            acc8(v3, a01, a23, a45, a67);
        }
        if (i < e) {
            unsigned e0 = desc[i + p8];
            unsigned e1 = desc[i + 8 + p8];
            uint4 v0 = hg128[(e0 << 3) + fp3];
            uint4 v1 = hg128[(e1 << 3) + fp3];
            acc8(v0, a01, a23, a45, a67);
            acc8(v1, a01, a23, a45, a67);
        }
        float dv = dinv[local];
        f32x2 dv2 = {dv, dv};
        a01 *= dv2; a23 *= dv2; a45 *= dv2; a67 *= dv2;
        float a0 = a01.x, a1 = a01.y, a2 = a23.x, a3 = a23.y;
        float a4 = a45.x, a5 = a45.y, a6 = a67.x, a7 = a67.y;
        a0 += __shfl_xor(a0, 8); a0 += __shfl_xor(a0, 16); a0 += __shfl_xor(a0, 32);
        a1 += __shfl_xor(a1, 8); a1 += __shfl_xor(a1, 16); a1 += __shfl_xor(a1, 32);
        a2 += __shfl_xor(a2, 8); a2 += __shfl_xor(a2, 16); a2 += __shfl_xor(a2, 32);
        a3 += __shfl_xor(a3, 8); a3 += __shfl_xor(a3, 16); a3 += __shfl_xor(a3, 32);
        a4 += __shfl_xor(a4, 8); a4 += __shfl_xor(a4, 16); a4 += __shfl_xor(a4, 32);
        a5 += __shfl_xor(a5, 8); a5 += __shfl_xor(a5, 16); a5 += __shfl_xor(a5, 32);
        a6 += __shfl_xor(a6, 8); a6 += __shfl_xor(a6, 16); a6 += __shfl_xor(a6, 32);
        a7 += __shfl_xor(a7, 8); a7 += __shfl_xor(a7, 16); a7 += __shfl_xor(a7, 32);
        if (p8 == 0) {
            float4* dst = (float4*)&tile[m * 68 + (fp3 << 3)];
            dst[0] = make_float4(a0, a1, a2, a3);
            dst[1] = make_float4(a4, a5, a6, a7);
        }
        if (lane == 0) dinvt[m] = dv;
    }
}

__device__ __forceinline__ f32x4 transform_tile(
        const float* tile, const short8* __restrict__ fb,
        const float* __restrict__ wf, int boff, int lane, int wv) {
    short8 Bh0 = fb[(wv << 8) +   0 + lane];
    short8 Bl0 = fb[(wv << 8) +  64 + lane];
    short8 Bh1 = fb[(wv << 8) + 128 + lane];
    short8 Bl1 = fb[(wv << 8) + 192 + lane];
    int mrow = lane & 15, quad = lane >> 4;
    const float* arow = &tile[mrow * 68];
    float4 a0 = *(const float4*)(arow + (quad << 3));
    float4 a1 = *(const float4*)(arow + (quad << 3) + 4);
    float4 a2 = *(const float4*)(arow + 32 + (quad << 3));
    float4 a3 = *(const float4*)(arow + 32 + (quad << 3) + 4);
    float av0[8] = {a0.x, a0.y, a0.z, a0.w, a1.x, a1.y, a1.z, a1.w};
    float av1[8] = {a2.x, a2.y, a2.z, a2.w, a3.x, a3.y, a3.z, a3.w};
    short8 Ah0, Al0, Ah1, Al1;
    #pragma unroll
    for (int j = 0; j < 8; ++j) {
        unsigned short h0 = f2bf(av0[j]);
        Ah0[j] = (short)h0; Al0[j] = (short)f2bf(av0[j] - bf2f(h0));
        unsigned short h1 = f2bf(av1[j]);
        Ah1[j] = (short)h1; Al1[j] = (short)f2bf(av1[j] - bf2f(h1));
    }
    float bias = wf[boff + (wv << 4) + mrow];
    f32x4 c = {bias, bias, bias, bias};
    c = __builtin_amdgcn_mfma_f32_16x16x32_bf16(Ah0, Bh0, c, 0, 0, 0);
    c = __builtin_amdgcn_mfma_f32_16x16x32_bf16(Al0, Bh0, c, 0, 0, 0);
    c = __builtin_amdgcn_mfma_f32_16x16x32_bf16(Ah0, Bl0, c, 0, 0, 0);
    c = __builtin_amdgcn_mfma_f32_16x16x32_bf16(Ah1, Bh1, c, 0, 0, 0);
    c = __builtin_amdgcn_mfma_f32_16x16x32_bf16(Al1, Bh1, c, 0, 0, 0);
    c = __builtin_amdgcn_mfma_f32_16x16x32_bf16(Ah1, Bl1, c, 0, 0, 0);
    return c;
}

// ================= persistent ODE kernel =================
// One regular launch replaces 181. Co-residency by construction:
// __launch_bounds__(256,4) caps VGPR<=128 -> 4 blocks/CU x 256 CU = 1024 >= 1000.
// Per-graph barriers (125 arrivals, g = blockIdx&7): graphs drift independently,
// so one graph's barrier spin overlaps other graphs' compute. Spin has a timeout
// + global dead flag: a deadlock degrades to a bounded wrong-answer, not a hang.

struct OdeArgs {
    unsigned short* hA; unsigned short* hB;
    float* yin; float* yb; float* kA; float* kB; float* kC; float* s4;
    const unsigned short* desc; const int* rowp; const float* dinv;
    const float* wf; const short8* frag;
    unsigned* bars; const int* modes; void* out;
};

__global__ __launch_bounds__(256, 4) void k_ode(OdeArgs A) {
    __shared__ float tile[16 * 68];
    __shared__ float dinvt[16];
    __shared__ float pd[4][16];
    __shared__ int sdead;

    const int b = blockIdx.x;
    const int g = b & 7, tb = (b >> 3) << 4;
    const int lane = threadIdx.x & 63, wv = threadIdx.x >> 6;
    const int fmode = A.modes[0];

    const unsigned short* __restrict__ desc = A.desc;
    const int* __restrict__ rowp = A.rowp;
    const float* __restrict__ dinvp = A.dinv;
    const float* __restrict__ wf = A.wf;
    const short8* __restrict__ frag = A.frag;
    unsigned* bar  = A.bars + (g << 6);   // 64B-separated per-graph counters
    unsigned* dead = A.bars + 509;        // global abort flag
    unsigned epoch = 0;

    // per-graph arrive-and-wait barrier (monotone counter, no reset)
    auto gbar = [&]() -> bool {
        __syncthreads();                       // all block stores drained
        ++epoch;
        if (threadIdx.x == 0) {
            // agent-scope release publishes this block's stores (L2 wb)
            __hip_atomic_fetch_add(bar, 1u, __ATOMIC_RELEASE, __HIP_MEMORY_SCOPE_AGENT);
            const unsigned tgt = epoch * (unsigned)TILES;
            unsigned it = 0; int ok = 1;
            while (__hip_atomic_load(bar, __ATOMIC_RELAXED, __HIP_MEMORY_SCOPE_AGENT) < tgt) {
                __builtin_amdgcn_s_sleep(2);
                if ((++it & 4095u) == 0u) {
                    if (it > 2000000u ||
                        __hip_atomic_load(dead, __ATOMIC_RELAXED, __HIP_MEMORY_SCOPE_AGENT) != 0u) {
                        __hip_atomic_store(dead, 1u, __ATOMIC_RELAXED, __HIP_MEMORY_SCOPE_AGENT);
                        ok = 0; break;
                    }
                }
            }
            __threadfence();                   // acquire: invalidate L1 + local L2
            sdead = ok ? 0 : 1;
        }
        __syncthreads();
        return sdead == 0;
    };

    auto do_layer0 = [&]() {                   // scalar gather -> 64-wide h, writes hA
        const float* yg = A.yin + g * PITCH;
        int grp = lane >> 4, j = lane & 15;
        int local = tb + (wv << 2) + grp;
        int s = rowp[local], e = rowp[local + 1];
        float acc = 0.f;
        for (int i = s + j; i < e; i += 16) acc += yg[desc[i]];
        acc += __shfl_xor(acc, 1); acc += __shfl_xor(acc, 2);
        acc += __shfl_xor(acc, 4); acc += __shfl_xor(acc, 8);
        float w0 = wf[W0OFF + lane], b0 = wf[B0OFF + lane];
        #pragma unroll
        for (int r = 0; r < 4; ++r) {
            float Z = __shfl(acc, r << 4);
            int ln = tb + (wv << 2) + r;
            float dv = dinvp[ln];
            float o = dv * tanh_fast(dv * Z * w0 + b0);
            A.hA[((size_t)(g * PITCH + ln) << 6) + lane] = f2bf(o);
        }
    };

    auto do_heavy = [&](const unsigned short* hin, unsigned short* hout,
                        int mat, int boff) {
        const uint4* hg128 = (const uint4*)(hin + ((size_t)g * PITCH << 6));
        gather_tile(hg128, desc, rowp, dinvp, tb, lane, wv, tile, dinvt);
        __syncthreads();
        f32x4 c = transform_tile(tile, frag + (mat << 10), wf, boff, lane, wv);
        int mrow = lane & 15, quad = lane >> 4;
        #pragma unroll
        for (int r = 0; r < 4; ++r) {
            int m = (quad << 2) + r;
            hout[(((size_t)g * PITCH + tb + m) << 6) + (wv << 4) + mrow] =
                f2bf(dinvt[m] * tanh_fast(c[r]));
        }
    };

    auto do_heavy_fuse = [&](const unsigned short* hin, int mat, int boff) {
        const uint4* hg128 = (const uint4*)(hin + ((size_t)g * PITCH << 6));
        gather_tile(hg128, desc, rowp, dinvp, tb, lane, wv, tile, dinvt);
        __syncthreads();
        f32x4 c = transform_tile(tile, frag + (mat << 10), wf, boff, lane, wv);
        int mrow = lane & 15, quad = lane >> 4;
        float w4v = wf[W4OFF + (wv << 4) + mrow];
        #pragma unroll
        for (int r = 0; r < 4; ++r) {
            float d = tanh_fast(c[r]) * w4v;
            d += __shfl_xor(d, 1); d += __shfl_xor(d, 2);
            d += __shfl_xor(d, 4); d += __shfl_xor(d, 8);
            if (mrow == 0) pd[wv][(quad << 2) + r] = d;
        }
        __syncthreads();
        if (threadIdx.x < 16)
            A.s4[g * PITCH + tb + threadIdx.x] = dinvt[threadIdx.x] *
                (pd[0][threadIdx.x] + pd[1][threadIdx.x] + pd[2][threadIdx.x] + pd[3][threadIdx.x]);
    };

    auto do_prop = [&](float c1, float c2, float c3, float c4, int stage, int hidx) {
        const float* sg = A.s4 + g * PITCH;
        int grp = lane >> 4, j = lane & 15;
        int local = tb + (wv << 2) + grp;
        int s = rowp[local], e = rowp[local + 1];
        float acc = 0.f;
        for (int i = s + j; i < e; i += 16) acc += sg[desc[i]];
        acc += __shfl_xor(acc, 1); acc += __shfl_xor(acc, 2);
        acc += __shfl_xor(acc, 4); acc += __shfl_xor(acc, 8);
        if (j == 0) {
            int idx = g * PITCH + local;
            float dv = dinvp[local];
            float k = dv * acc + wf[B4OFF];
            float ynew = A.yb[idx] + c1 * A.kA[idx] + c2 * A.kB[idx] + c3 * A.kC[idx] + c4 * k;
            if (stage == 0) A.kA[idx] = k;
            else if (stage == 1) A.kB[idx] = k;
            else if (stage == 2) A.kC[idx] = k;
            A.yin[idx] = dv * ynew;
            if (stage == 3) {
                A.yb[idx] = ynew;
                int cn = g * NNODE + local;
                if (fmode) ((__hip_bfloat16*)A.out)[cn * HOR + hidx] = __float2bfloat16(ynew);
                else       ((float*)A.out)[cn * HOR + hidx] = ynew;
            }
        }
    };

    const float dt = 10.f / 9.f, dt3 = dt / 3.f;

    do_layer0(); if (!gbar()) return;
    for (int it = 0; it < 4 * NSTEP; ++it) {
        int st = it & 3, step = it >> 2;
        float c1 = (st == 1) ? -dt3 : (st == 2) ? dt : (st == 3) ? dt * 0.125f : 0.f;
        float c2 = (st == 2) ? -dt  : (st == 3) ? dt * 0.375f : 0.f;
        float c3 = (st == 3) ? dt * 0.375f : 0.f;
        float c4 = (st == 0) ? dt3  : (st == 3) ? dt * 0.125f : dt;

        do_heavy(A.hA, A.hB, 0, B1OFF); if (!gbar()) return;
        do_heavy(A.hB, A.hA, 1, B2OFF); if (!gbar()) return;
        do_heavy_fuse(A.hA, 2, B3OFF);  if (!gbar()) return;
        do_prop(c1, c2, c3, c4, st, step + 1); if (!gbar()) return;
        if (it != 4 * NSTEP - 1) { do_layer0(); if (!gbar()) return; }
    }
}

// ================= host =================

extern "C" void kernel_launch(void* const* d_in, const int* in_sizes, int n_in,
                              void* d_out, int out_size, void* d_ws, size_t ws_size,
                              hipStream_t stream) {
    char* ws = (char*)d_ws;
    unsigned short* desc = (unsigned short*)(ws + OFF_DESC);
    unsigned short* hA   = (unsigned short*)(ws + OFF_HA);
    unsigned short* hB   = (unsigned short*)(ws + OFF_HB);
    float* yin  = (float*)(ws + OFF_YIN);
    float* yb   = (float*)(ws + OFF_YB);
    float* kA   = (float*)(ws + OFF_KA);
    float* kB   = (float*)(ws + OFF_KB);
    float* kC   = (float*)(ws + OFF_KC);
    float* s4   = (float*)(ws + OFF_S4);
    int*   deg  = (int*)(ws + OFF_DEG);
    int*   cur  = (int*)(ws + OFF_CUR);
    int*   rowp = (int*)(ws + OFF_ROWP);
    float* dinv = (float*)(ws + OFF_DINV);
    int*   modes= (int*)(ws + OFF_MODES);
    float* wf   = (float*)(ws + OFF_WF);
    short8* wfrag = (short8*)(ws + OFF_WFRAG);
    unsigned* bars = (unsigned*)(ws + OFF_CUR);   // cursor region reused post-scatter

    const void* x    = d_in[0];
    const void* eidx = d_in[1];
    WPtrs wp;
    for (int i = 0; i < 10; ++i) wp.p[i] = d_in[2 + i];

    k_detect  <<<1, 64, 0, stream>>>(x, eidx, modes);
    k_setup0  <<<192, 256, 0, stream>>>(deg, (unsigned*)desc, (unsigned*)hA, (unsigned*)hB);
    k_count   <<<EPG / 256, 256, 0, stream>>>(eidx, modes, deg);
    k_scan    <<<1, 256, 0, stream>>>(deg, rowp, cur, dinv);
    k_scatter <<<(EPG + NNODE + 255) / 256, 256, 0, stream>>>(eidx, modes, cur, desc);
    k_convert <<<(WFTOT + 255) / 256, 256, 0, stream>>>(wp, wf, modes);
    k_mkfrag  <<<12, 256, 0, stream>>>(wf, wfrag);
    k_finalize<<<NG * PITCH / 256, 256, 0, stream>>>(dinv, x, modes, bars, yin, yb, s4, d_out);

    OdeArgs a;
    a.hA = hA; a.hB = hB; a.yin = yin; a.yb = yb; a.kA = kA; a.kB = kB; a.kC = kC;
    a.s4 = s4; a.desc = desc; a.rowp = rowp; a.dinv = dinv; a.wf = wf;
    a.frag = wfrag; a.bars = bars; a.modes = modes; a.out = d_out;
    k_ode<<<dim3(NG * TILES), dim3(256), 0, stream>>>(a);
}

// Round 3
// 3556.945 us; speedup vs baseline: 2.7241x; 2.7241x over previous
//
#include <hip/hip_runtime.h>
#include <hip/hip_bf16.h>

#define NNODE   2000
#define NG      8
#define EPG     64000
#define TSTEPS  24
#define HOR     10
#define NSTEP   (HOR-1)
#define PITCH   2048          // per-graph node pitch; row 2047 is the zero row
#define ECAP    98304         // padded CSR capacity (ushorts)
#define TILES   125           // 2000 / 16

// ---- workspace layout (bytes) ----
#define OFF_DESC    0
#define OFF_HA      196608
#define OFF_HB      2293760
#define OFF_YIN     4390912
#define OFF_YB      4456448
#define OFF_KA      4521984
#define OFF_KB      4587520
#define OFF_KC      4653056
#define OFF_S4      4718592
#define OFF_DEG     4784128
#define OFF_CUR     4792320   // cursor during setup; reused as barrier counters in k_ode
#define OFF_ROWP    4800512
#define OFF_DINV    4808960
#define OFF_MODES   4817152
#define OFF_WF      4817408
#define OFF_WFRAG   4868352
// total 4917504 B — identical to the proven footprint (no growth)

#define W0OFF 0
#define B0OFF 64
#define W1OFF 128
#define B1OFF 4224
#define W2OFF 4288
#define B2OFF 8384
#define W3OFF 8448
#define B3OFF 12544
#define W4OFF 12608
#define B4OFF 12672
#define WFTOT 12673

typedef __attribute__((ext_vector_type(8))) short short8;
typedef __attribute__((ext_vector_type(4))) float f32x4;
typedef __attribute__((ext_vector_type(2))) float f32x2;

struct WPtrs { const void* p[10]; };

__device__ inline float tanh_fast(float x) {
    float xc = fminf(fmaxf(x, -15.f), 15.f);
    float e  = __expf(2.f * xc);
    return 1.f - 2.f / (e + 1.f);
}
__device__ inline unsigned short f2bf(float f) {
    unsigned u = __float_as_uint(f);
    u += 0x7fff + ((u >> 16) & 1);
    return (unsigned short)(u >> 16);
}
__device__ inline float bf2f(unsigned short h) {
    return __uint_as_float(((unsigned)h) << 16);
}
__device__ inline int ld_idx(const void* p, long i, int imode) {
    return imode ? (int)((const long long*)p)[i] : ((const int*)p)[i];
}

// unpack one dword (2 bf16 feats) into a register-pair float2 -> feeds v_pk_add_f32
__device__ inline f32x2 unpk(unsigned v) {
    f32x2 r;
    r.x = __uint_as_float(v << 16);
    r.y = __uint_as_float(v & 0xffff0000u);
    return r;
}

// ================= setup kernels =================

__global__ void k_detect(const void* x, const void* eidx, int* modes) {
    int lane = threadIdx.x;
    const unsigned* xw = (const unsigned*)x;
    unsigned w = xw[lane];
    int ex = (w >> 7) & 0xFF;
    unsigned long long m = __ballot(ex >= 100 && ex <= 145);
    const unsigned* ew = (const unsigned*)eidx;
    unsigned long long m2 = __ballot(ew[2*lane + 1] != 0);
    if (lane == 0) {
        modes[0] = (__popcll(m) >= 48) ? 1 : 0;
        modes[1] = (__popcll(m2) == 0) ? 1 : 0;
    }
}

// merged: deg init + desc sentinel fill + h pad-row zeroing
__global__ void k_setup0(int* deg, unsigned* desc32, unsigned* hA32, unsigned* hB32) {
    int n = blockIdx.x * 256 + threadIdx.x;
    if (n < PITCH) deg[n] = (n < NNODE) ? 1 : 0;
    if (n < ECAP / 2) desc32[n] = 0x07FF07FFu;     // sentinel -> zero row 2047
    if (n < 2 * NG * 48 * 32) {
        int b = n / (NG * 48 * 32), r = n % (NG * 48 * 32);
        int g = r / (48 * 32), rr = r % (48 * 32);
        int row = NNODE + rr / 32, fp = rr % 32;
        unsigned* pp = b ? hB32 : hA32;
        pp[(g * PITCH + row) * 32 + fp] = 0;
    }
}

__global__ void k_count(const void* eidx, const int* __restrict__ modes, int* deg) {
    int e = blockIdx.x * 256 + threadIdx.x;
    int imode = modes[1];
    int dst = ld_idx(eidx, (long)EPG + e, imode);
    atomicAdd(&deg[dst], 1);
}

__global__ __launch_bounds__(256) void k_scan(const int* __restrict__ deg, int* rowp,
                                              int* cursor, float* dinv) {
    __shared__ int part[256];
    int t = threadIdx.x, base = t * 8;
    int loc[8]; int s = 0;
    #pragma unroll
    for (int k = 0; k < 8; ++k) {
        int d = deg[base + k];
        int p = (d + 15) & ~15;
        loc[k] = p; s += p;
    }
    part[t] = s; __syncthreads();
    for (int off = 1; off < 256; off <<= 1) {
        int v = (t >= off) ? part[t - off] : 0;
        __syncthreads();
        part[t] += v;
        __syncthreads();
    }
    int run = part[t] - s;
    #pragma unroll
    for (int k = 0; k < 8; ++k) {
        rowp[base + k] = run; cursor[base + k] = run;
        int d = deg[base + k];
        dinv[base + k] = (d > 0) ? rsqrtf((float)d) : 0.f;
        run += loc[k];
    }
    if (t == 255) rowp[PITCH] = part[255];
}

__global__ void k_scatter(const void* eidx, const int* __restrict__ modes,
                          int* cursor, unsigned short* desc) {
    int idx = blockIdx.x * 256 + threadIdx.x;
    if (idx >= EPG + NNODE) return;
    int imode = modes[1];
    int s, d;
    if (idx < EPG) { s = ld_idx(eidx, idx, imode); d = ld_idx(eidx, (long)EPG + idx, imode); }
    else           { s = idx - EPG; d = s; }
    int pos = atomicAdd(&cursor[d], 1);
    desc[pos] = (unsigned short)s;
}

__global__ void k_convert(WPtrs wp, float* wf, const int* __restrict__ modes) {
    int idx = blockIdx.x * 256 + threadIdx.x;
    if (idx >= WFTOT) return;
    int fmode = modes[0];
    const int offs[10]  = {W0OFF,B0OFF,W1OFF,B1OFF,W2OFF,B2OFF,W3OFF,B3OFF,W4OFF,B4OFF};
    const int sizes[10] = {64,64,4096,64,4096,64,4096,64,64,1};
    #pragma unroll
    for (int s = 0; s < 10; ++s) {
        if (idx >= offs[s] && idx < offs[s] + sizes[s]) {
            int j = idx - offs[s];
            wf[idx] = fmode ? __bfloat162float(((const __hip_bfloat16*)wp.p[s])[j])
                            : ((const float*)wp.p[s])[j];
        }
    }
}

__global__ void k_mkfrag(const float* __restrict__ wf, short8* frag) {
    int t = blockIdx.x * 256 + threadIdx.x;
    if (t >= 3072) return;
    int lane = t & 63, half = (t >> 6) & 1, kh = (t >> 7) & 1, nb = (t >> 8) & 3, mat = t >> 10;
    const int woffs[3] = {W1OFF, W2OFF, W3OFF};
    const float* W = wf + woffs[mat];
    int n  = nb * 16 + (lane & 15);
    int k0 = kh * 32 + (lane >> 4) * 8;
    short8 v;
    #pragma unroll
    for (int j = 0; j < 8; ++j) {
        float w = W[(k0 + j) * 64 + n];
        unsigned short h = f2bf(w);
        v[j] = half ? (short)f2bf(w - bf2f(h)) : (short)h;
    }
    frag[t] = v;
}

// also zeroes the barrier counters (relocated into the dead cursor region)
__global__ void k_finalize(const float* __restrict__ dinv, const void* x,
                           const int* __restrict__ modes, unsigned* bars,
                           float* yin, float* yb, float* s4, void* out) {
    int idx = blockIdx.x * 256 + threadIdx.x;
    if (idx < 512) bars[idx] = 0u;
    if (idx >= NG * PITCH) return;
    int g = idx >> 11, local = idx & (PITCH - 1);
    if (local >= NNODE) { yin[idx] = 0.f; yb[idx] = 0.f; s4[idx] = 0.f; return; }
    int cn = g * NNODE + local;
    float y0 = modes[0] ? __bfloat162float(((const __hip_bfloat16*)x)[cn * TSTEPS + (TSTEPS - 1)])
                        : ((const float*)x)[cn * TSTEPS + (TSTEPS - 1)];
    yin[idx] = dinv[local] * y0;
    yb[idx]  = y0;
    if (modes[0]) ((__hip_bfloat16*)out)[cn * HOR] = __float2bfloat16(y0);
    else          ((float*)out)[cn * HOR] = y0;
}

// ---- heavy gather: dwordx4 rows, 32-edge unroll, packed f32x2 accumulators ----
__device__ __forceinline__ void acc8(uint4 v, f32x2& a01, f32x2& a23,
                                     f32x2& a45, f32x2& a67) {
    a01 += unpk(v.x);
    a23 += unpk(v.y);
    a45 += unpk(v.z);
    a67 += unpk(v.w);
}

__device__ __forceinline__ void gather_tile(
        const uint4* __restrict__ hg128, const unsigned short* __restrict__ desc,
        const int* __restrict__ rowp, const float* __restrict__ dinv,
        int tb, int lane, int wv, float* tile, float* dinvt) {
    int fp3 = lane & 7, p8 = lane >> 3;
    #pragma unroll
    for (int r = 0; r < 4; ++r) {
        int m = (wv << 2) + r;
        int local = tb + m;
        int s = rowp[local], e = rowp[local + 1];   // multiples of 16
        f32x2 a01 = {0.f, 0.f}, a23 = {0.f, 0.f}, a45 = {0.f, 0.f}, a67 = {0.f, 0.f};
        int i = s;
        for (; i + 32 <= e; i += 32) {
            unsigned e0 = desc[i + p8];
            unsigned e1 = desc[i + 8 + p8];
            unsigned e2 = desc[i + 16 + p8];
            unsigned e3 = desc[i + 24 + p8];
            uint4 v0 = hg128[(e0 << 3) + fp3];
            uint4 v1 = hg128[(e1 << 3) + fp3];
            uint4 v2 = hg128[(e2 << 3) + fp3];
            uint4 v3 = hg128[(e3 << 3) + fp3];
            acc8(v0, a01, a23, a45, a67);
            acc8(v1, a01, a23, a45, a67);
            acc8(v2, a01, a23, a45, a67);
            acc8(v3, a01, a23, a45, a67);
        }
        if (i < e) {
            unsigned e0 = desc[i + p8];
            unsigned e1 = desc[i + 8 + p8];
            uint4 v0 = hg128[(e0 << 3) + fp3];
            uint4 v1 = hg128[(e1 << 3) + fp3];
            acc8(v0, a01, a23, a45, a67);
            acc8(v1, a01, a23, a45, a67);
        }
        float dv = dinv[local];
        f32x2 dv2 = {dv, dv};
        a01 *= dv2; a23 *= dv2; a45 *= dv2; a67 *= dv2;
        float a0 = a01.x, a1 = a01.y, a2 = a23.x, a3 = a23.y;
        float a4 = a45.x, a5 = a45.y, a6 = a67.x, a7 = a67.y;
        a0 += __shfl_xor(a0, 8); a0 += __shfl_xor(a0, 16); a0 += __shfl_xor(a0, 32);
        a1 += __shfl_xor(a1, 8); a1 += __shfl_xor(a1, 16); a1 += __shfl_xor(a1, 32);
        a2 += __shfl_xor(a2, 8); a2 += __shfl_xor(a2, 16); a2 += __shfl_xor(a2, 32);
        a3 += __shfl_xor(a3, 8); a3 += __shfl_xor(a3, 16); a3 += __shfl_xor(a3, 32);
        a4 += __shfl_xor(a4, 8); a4 += __shfl_xor(a4, 16); a4 += __shfl_xor(a4, 32);
        a5 += __shfl_xor(a5, 8); a5 += __shfl_xor(a5, 16); a5 += __shfl_xor(a5, 32);
        a6 += __shfl_xor(a6, 8); a6 += __shfl_xor(a6, 16); a6 += __shfl_xor(a6, 32);
        a7 += __shfl_xor(a7, 8); a7 += __shfl_xor(a7, 16); a7 += __shfl_xor(a7, 32);
        if (p8 == 0) {
            float4* dst = (float4*)&tile[m * 68 + (fp3 << 3)];
            dst[0] = make_float4(a0, a1, a2, a3);
            dst[1] = make_float4(a4, a5, a6, a7);
        }
        if (lane == 0) dinvt[m] = dv;
    }
}

__device__ __forceinline__ f32x4 transform_tile(
        const float* tile, const short8* __restrict__ fb,
        const float* __restrict__ wf, int boff, int lane, int wv) {
    short8 Bh0 = fb[(wv << 8) +   0 + lane];
    short8 Bl0 = fb[(wv << 8) +  64 + lane];
    short8 Bh1 = fb[(wv << 8) + 128 + lane];
    short8 Bl1 = fb[(wv << 8) + 192 + lane];
    int mrow = lane & 15, quad = lane >> 4;
    const float* arow = &tile[mrow * 68];
    float4 a0 = *(const float4*)(arow + (quad << 3));
    float4 a1 = *(const float4*)(arow + (quad << 3) + 4);
    float4 a2 = *(const float4*)(arow + 32 + (quad << 3));
    float4 a3 = *(const float4*)(arow + 32 + (quad << 3) + 4);
    float av0[8] = {a0.x, a0.y, a0.z, a0.w, a1.x, a1.y, a1.z, a1.w};
    float av1[8] = {a2.x, a2.y, a2.z, a2.w, a3.x, a3.y, a3.z, a3.w};
    short8 Ah0, Al0, Ah1, Al1;
    #pragma unroll
    for (int j = 0; j < 8; ++j) {
        unsigned short h0 = f2bf(av0[j]);
        Ah0[j] = (short)h0; Al0[j] = (short)f2bf(av0[j] - bf2f(h0));
        unsigned short h1 = f2bf(av1[j]);
        Ah1[j] = (short)h1; Al1[j] = (short)f2bf(av1[j] - bf2f(h1));
    }
    float bias = wf[boff + (wv << 4) + mrow];
    f32x4 c = {bias, bias, bias, bias};
    c = __builtin_amdgcn_mfma_f32_16x16x32_bf16(Ah0, Bh0, c, 0, 0, 0);
    c = __builtin_amdgcn_mfma_f32_16x16x32_bf16(Al0, Bh0, c, 0, 0, 0);
    c = __builtin_amdgcn_mfma_f32_16x16x32_bf16(Ah0, Bl0, c, 0, 0, 0);
    c = __builtin_amdgcn_mfma_f32_16x16x32_bf16(Ah1, Bh1, c, 0, 0, 0);
    c = __builtin_amdgcn_mfma_f32_16x16x32_bf16(Al1, Bh1, c, 0, 0, 0);
    c = __builtin_amdgcn_mfma_f32_16x16x32_bf16(Ah1, Bl1, c, 0, 0, 0);
    return c;
}

// ================= persistent ODE kernel =================
// One launch replaces 181. Key fix vs the 9.7ms version: NO L2 writeback/inv
// at barriers. g = blockIdx&7 -> all 125 blocks of a graph land on one XCD
// (HW round-robin), so same-XCD L2 is the coherence point; barriers only need
// vmcnt drain + per-CU L1 invalidate (buffer_inv sc0). Mapping is VERIFIED at
// runtime via HW_REG_XCC_ID; non-uniform graphs fall back to the proven (slow)
// agent-fence barrier. First barrier is always the slow one.

struct OdeArgs {
    unsigned short* hA; unsigned short* hB;
    float* yin; float* yb; float* kA; float* kB; float* kC; float* s4;
    const unsigned short* desc; const int* rowp; const float* dinv;
    const float* wf; const short8* frag;
    unsigned* bars; const int* modes; void* out;
};

__global__ __launch_bounds__(256, 4) void k_ode(OdeArgs A) {
    __shared__ float tile[16 * 68];
    __shared__ float dinvt[16];
    __shared__ float pd[4][16];
    __shared__ int sdead;
    __shared__ int sfast;

    const int b = blockIdx.x;
    const int g = b & 7, tb = (b >> 3) << 4;
    const int lane = threadIdx.x & 63, wv = threadIdx.x >> 6;
    const int fmode = A.modes[0];

    const unsigned short* __restrict__ desc = A.desc;
    const int* __restrict__ rowp = A.rowp;
    const float* __restrict__ dinvp = A.dinv;
    const float* __restrict__ wf = A.wf;
    const short8* __restrict__ frag = A.frag;
    unsigned* bar  = A.bars + (g << 6);   // 256B-separated per-graph counters
    unsigned* xccm = A.bars + 480 + g;    // per-graph XCC-mask
    unsigned* dead = A.bars + 509;        // global abort flag
    unsigned epoch = 0;

    // report this block's XCD (device-scope atomic; published by first slow barrier)
    if (threadIdx.x == 0) {
        unsigned xcc;
        asm volatile("s_getreg_b32 %0, hwreg(HW_REG_XCC_ID, 0, 4)" : "=s"(xcc));
        atomicOr(xccm, 1u << (xcc & 15u));
    }

    // per-graph arrive-and-wait barrier (monotone counter, no reset)
    auto gbar = [&](bool fast) -> bool {
        __syncthreads();                       // all waves drained vmcnt before s_barrier
        ++epoch;
        if (threadIdx.x == 0) {
            if (fast) {
                asm volatile("s_waitcnt vmcnt(0)" ::: "memory");
                __hip_atomic_fetch_add(bar, 1u, __ATOMIC_RELAXED, __HIP_MEMORY_SCOPE_AGENT);
            } else {
                // agent release: L2 writeback (cross-XCD safe, slow)
                __hip_atomic_fetch_add(bar, 1u, __ATOMIC_RELEASE, __HIP_MEMORY_SCOPE_AGENT);
            }
            const unsigned tgt = epoch * (unsigned)TILES;
            unsigned it = 0; int ok = 1;
            while (__hip_atomic_load(bar, __ATOMIC_RELAXED, __HIP_MEMORY_SCOPE_AGENT) < tgt) {
                __builtin_amdgcn_s_sleep(4);
                if ((++it & 2047u) == 0u) {
                    if (it > 3000000u ||
                        __hip_atomic_load(dead, __ATOMIC_RELAXED, __HIP_MEMORY_SCOPE_AGENT) != 0u) {
                        __hip_atomic_store(dead, 1u, __ATOMIC_RELAXED, __HIP_MEMORY_SCOPE_AGENT);
                        ok = 0; break;
                    }
                }
            }
            if (fast) {
                // L1-only invalidate (per-CU); data is in the shared same-XCD L2
                asm volatile("buffer_inv sc0\n\ts_waitcnt vmcnt(0)" ::: "memory");
            } else {
                __threadfence();               // agent acquire: L2 invalidate
            }
            sdead = ok ? 0 : 1;
        }
        __syncthreads();
        return sdead == 0;
    };

    auto do_layer0 = [&]() {                   // scalar gather -> 64-wide h, writes hA
        const float* yg = A.yin + g * PITCH;
        int grp = lane >> 4, j = lane & 15;
        int local = tb + (wv << 2) + grp;
        int s = rowp[local], e = rowp[local + 1];
        float acc = 0.f;
        for (int i = s + j; i < e; i += 16) acc += yg[desc[i]];
        acc += __shfl_xor(acc, 1); acc += __shfl_xor(acc, 2);
        acc += __shfl_xor(acc, 4); acc += __shfl_xor(acc, 8);
        float w0 = wf[W0OFF + lane], b0 = wf[B0OFF + lane];
        #pragma unroll
        for (int r = 0; r < 4; ++r) {
            float Z = __shfl(acc, r << 4);
            int ln = tb + (wv << 2) + r;
            float dv = dinvp[ln];
            float o = dv * tanh_fast(dv * Z * w0 + b0);
            A.hA[((size_t)(g * PITCH + ln) << 6) + lane] = f2bf(o);
        }
    };

    auto do_heavy = [&](const unsigned short* hin, unsigned short* hout,
                        int mat, int boff) {
        const uint4* hg128 = (const uint4*)(hin + ((size_t)g * PITCH << 6));
        gather_tile(hg128, desc, rowp, dinvp, tb, lane, wv, tile, dinvt);
        __syncthreads();
        f32x4 c = transform_tile(tile, frag + (mat << 10), wf, boff, lane, wv);
        int mrow = lane & 15, quad = lane >> 4;
        #pragma unroll
        for (int r = 0; r < 4; ++r) {
            int m = (quad << 2) + r;
            hout[(((size_t)g * PITCH + tb + m) << 6) + (wv << 4) + mrow] =
                f2bf(dinvt[m] * tanh_fast(c[r]));
        }
    };

    auto do_heavy_fuse = [&](const unsigned short* hin, int mat, int boff) {
        const uint4* hg128 = (const uint4*)(hin + ((size_t)g * PITCH << 6));
        gather_tile(hg128, desc, rowp, dinvp, tb, lane, wv, tile, dinvt);
        __syncthreads();
        f32x4 c = transform_tile(tile, frag + (mat << 10), wf, boff, lane, wv);
        int mrow = lane & 15, quad = lane >> 4;
        float w4v = wf[W4OFF + (wv << 4) + mrow];
        #pragma unroll
        for (int r = 0; r < 4; ++r) {
            float d = tanh_fast(c[r]) * w4v;
            d += __shfl_xor(d, 1); d += __shfl_xor(d, 2);
            d += __shfl_xor(d, 4); d += __shfl_xor(d, 8);
            if (mrow == 0) pd[wv][(quad << 2) + r] = d;
        }
        __syncthreads();
        if (threadIdx.x < 16)
            A.s4[g * PITCH + tb + threadIdx.x] = dinvt[threadIdx.x] *
                (pd[0][threadIdx.x] + pd[1][threadIdx.x] + pd[2][threadIdx.x] + pd[3][threadIdx.x]);
    };

    auto do_prop = [&](float c1, float c2, float c3, float c4, int stage, int hidx) {
        const float* sg = A.s4 + g * PITCH;
        int grp = lane >> 4, j = lane & 15;
        int local = tb + (wv << 2) + grp;
        int s = rowp[local], e = rowp[local + 1];
        float acc = 0.f;
        for (int i = s + j; i < e; i += 16) acc += sg[desc[i]];
        acc += __shfl_xor(acc, 1); acc += __shfl_xor(acc, 2);
        acc += __shfl_xor(acc, 4); acc += __shfl_xor(acc, 8);
        if (j == 0) {
            int idx = g * PITCH + local;
            float dv = dinvp[local];
            float k = dv * acc + wf[B4OFF];
            float ynew = A.yb[idx] + c1 * A.kA[idx] + c2 * A.kB[idx] + c3 * A.kC[idx] + c4 * k;
            if (stage == 0) A.kA[idx] = k;
            else if (stage == 1) A.kB[idx] = k;
            else if (stage == 2) A.kC[idx] = k;
            A.yin[idx] = dv * ynew;
            if (stage == 3) {
                A.yb[idx] = ynew;
                int cn = g * NNODE + local;
                if (fmode) ((__hip_bfloat16*)A.out)[cn * HOR + hidx] = __float2bfloat16(ynew);
                else       ((float*)A.out)[cn * HOR + hidx] = ynew;
            }
        }
    };

    const float dt = 10.f / 9.f, dt3 = dt / 3.f;

    do_layer0();
    if (!gbar(false)) return;                  // slow barrier #1 publishes xccm

    if (threadIdx.x == 0) {
        unsigned m = __hip_atomic_load(xccm, __ATOMIC_RELAXED, __HIP_MEMORY_SCOPE_AGENT);
        sfast = (__popc(m) == 1) ? 1 : 0;      // all 125 blocks on one XCD?
    }
    __syncthreads();
    const bool fast = (sfast != 0);

    for (int it = 0; it < 4 * NSTEP; ++it) {
        int st = it & 3, step = it >> 2;
        float c1 = (st == 1) ? -dt3 : (st == 2) ? dt : (st == 3) ? dt * 0.125f : 0.f;
        float c2 = (st == 2) ? -dt  : (st == 3) ? dt * 0.375f : 0.f;
        float c3 = (st == 3) ? dt * 0.375f : 0.f;
        float c4 = (st == 0) ? dt3  : (st == 3) ? dt * 0.125f : dt;

        do_heavy(A.hA, A.hB, 0, B1OFF); if (!gbar(fast)) return;
        do_heavy(A.hB, A.hA, 1, B2OFF); if (!gbar(fast)) return;
        do_heavy_fuse(A.hA, 2, B3OFF);  if (!gbar(fast)) return;
        do_prop(c1, c2, c3, c4, st, step + 1); if (!gbar(fast)) return;
        if (it != 4 * NSTEP - 1) { do_layer0(); if (!gbar(fast)) return; }
    }
}

// ================= host =================

extern "C" void kernel_launch(void* const* d_in, const int* in_sizes, int n_in,
                              void* d_out, int out_size, void* d_ws, size_t ws_size,
                              hipStream_t stream) {
    char* ws = (char*)d_ws;
    unsigned short* desc = (unsigned short*)(ws + OFF_DESC);
    unsigned short* hA   = (unsigned short*)(ws + OFF_HA);
    unsigned short* hB   = (unsigned short*)(ws + OFF_HB);
    float* yin  = (float*)(ws + OFF_YIN);
    float* yb   = (float*)(ws + OFF_YB);
    float* kA   = (float*)(ws + OFF_KA);
    float* kB   = (float*)(ws + OFF_KB);
    float* kC   = (float*)(ws + OFF_KC);
    float* s4   = (float*)(ws + OFF_S4);
    int*   deg  = (int*)(ws + OFF_DEG);
    int*   cur  = (int*)(ws + OFF_CUR);
    int*   rowp = (int*)(ws + OFF_ROWP);
    float* dinv = (float*)(ws + OFF_DINV);
    int*   modes= (int*)(ws + OFF_MODES);
    float* wf   = (float*)(ws + OFF_WF);
    short8* wfrag = (short8*)(ws + OFF_WFRAG);
    unsigned* bars = (unsigned*)(ws + OFF_CUR);   // cursor region reused post-scatter

    const void* x    = d_in[0];
    const void* eidx = d_in[1];
    WPtrs wp;
    for (int i = 0; i < 10; ++i) wp.p[i] = d_in[2 + i];

    k_detect  <<<1, 64, 0, stream>>>(x, eidx, modes);
    k_setup0  <<<192, 256, 0, stream>>>(deg, (unsigned*)desc, (unsigned*)hA, (unsigned*)hB);
    k_count   <<<EPG / 256, 256, 0, stream>>>(eidx, modes, deg);
    k_scan    <<<1, 256, 0, stream>>>(deg, rowp, cur, dinv);
    k_scatter <<<(EPG + NNODE + 255) / 256, 256, 0, stream>>>(eidx, modes, cur, desc);
    k_convert <<<(WFTOT + 255) / 256, 256, 0, stream>>>(wp, wf, modes);
    k_mkfrag  <<<12, 256, 0, stream>>>(wf, wfrag);
    k_finalize<<<NG * PITCH / 256, 256, 0, stream>>>(dinv, x, modes, bars, yin, yb, s4, d_out);

    OdeArgs a;
    a.hA = hA; a.hB = hB; a.yin = yin; a.yb = yb; a.kA = kA; a.kB = kB; a.kC = kC;
    a.s4 = s4; a.desc = desc; a.rowp = rowp; a.dinv = dinv; a.wf = wf;
    a.frag = wfrag; a.bars = bars; a.modes = modes; a.out = d_out;
    k_ode<<<dim3(NG * TILES), dim3(256), 0, stream>>>(a);
}

// Round 5
// 3318.964 us; speedup vs baseline: 2.9195x; 1.0717x over previous
//
#include <hip/hip_runtime.h>
#include <hip/hip_bf16.h>

#define NNODE   2000
#define NG      8
#define EPG     64000
#define TSTEPS  24
#define HOR     10
#define NSTEP   (HOR-1)
#define PITCH   2048          // per-graph node pitch; row 2047 is the zero row
#define ECAP    98304         // padded CSR capacity (ushorts)
#define TILES   125           // 2000 / 16

// ---- workspace layout (bytes) ----
#define OFF_DESC    0
#define OFF_HA      196608
#define OFF_HB      2293760
#define OFF_YIN     4390912
#define OFF_YB      4456448
#define OFF_KA      4521984
#define OFF_KB      4587520
#define OFF_KC      4653056
#define OFF_S4      4718592
#define OFF_DEG     4784128
#define OFF_CUR     4792320   // cursor during setup; reused as barrier counters in k_ode
#define OFF_ROWP    4800512
#define OFF_DINV    4808960
#define OFF_MODES   4817152
#define OFF_WF      4817408
#define OFF_WFRAG   4868352
// total 4917504 B — identical to the proven footprint (no growth)

#define W0OFF 0
#define B0OFF 64
#define W1OFF 128
#define B1OFF 4224
#define W2OFF 4288
#define B2OFF 8384
#define W3OFF 8448
#define B3OFF 12544
#define W4OFF 12608
#define B4OFF 12672
#define WFTOT 12673

typedef __attribute__((ext_vector_type(8))) short short8;
typedef __attribute__((ext_vector_type(4))) float f32x4;
typedef __attribute__((ext_vector_type(2))) float f32x2;

#define U64(p) ((unsigned long long)(p))

struct WPtrs { const void* p[10]; };

__device__ inline float tanh_fast(float x) {
    float xc = fminf(fmaxf(x, -15.f), 15.f);
    float e  = __expf(2.f * xc);
    return 1.f - 2.f / (e + 1.f);
}
__device__ inline unsigned short f2bf(float f) {
    unsigned u = __float_as_uint(f);
    u += 0x7fff + ((u >> 16) & 1);
    return (unsigned short)(u >> 16);
}
__device__ inline float bf2f(unsigned short h) {
    return __uint_as_float(((unsigned)h) << 16);
}
__device__ inline int ld_idx(const void* p, long i, int imode) {
    return imode ? (int)((const long long*)p)[i] : ((const int*)p)[i];
}

// unpack one dword (2 bf16 feats) into a register-pair float2 -> feeds v_pk_add_f32
__device__ inline f32x2 unpk(unsigned v) {
    f32x2 r;
    r.x = __uint_as_float(v << 16);
    r.y = __uint_as_float(v & 0xffff0000u);
    return r;
}

// ================= setup kernels =================

__global__ void k_detect(const void* x, const void* eidx, int* modes) {
    int lane = threadIdx.x;
    const unsigned* xw = (const unsigned*)x;
    unsigned w = xw[lane];
    int ex = (w >> 7) & 0xFF;
    unsigned long long m = __ballot(ex >= 100 && ex <= 145);
    const unsigned* ew = (const unsigned*)eidx;
    unsigned long long m2 = __ballot(ew[2*lane + 1] != 0);
    if (lane == 0) {
        modes[0] = (__popcll(m) >= 48) ? 1 : 0;
        modes[1] = (__popcll(m2) == 0) ? 1 : 0;
    }
}

// merged: deg init + desc sentinel fill + h pad-row zeroing
__global__ void k_setup0(int* deg, unsigned* desc32, unsigned* hA32, unsigned* hB32) {
    int n = blockIdx.x * 256 + threadIdx.x;
    if (n < PITCH) deg[n] = (n < NNODE) ? 1 : 0;
    if (n < ECAP / 2) desc32[n] = 0x07FF07FFu;     // sentinel -> zero row 2047
    if (n < 2 * NG * 48 * 32) {
        int b = n / (NG * 48 * 32), r = n % (NG * 48 * 32);
        int g = r / (48 * 32), rr = r % (48 * 32);
        int row = NNODE + rr / 32, fp = rr % 32;
        unsigned* pp = b ? hB32 : hA32;
        pp[(g * PITCH + row) * 32 + fp] = 0;
    }
}

__global__ void k_count(const void* eidx, const int* __restrict__ modes, int* deg) {
    int e = blockIdx.x * 256 + threadIdx.x;
    int imode = modes[1];
    int dst = ld_idx(eidx, (long)EPG + e, imode);
    atomicAdd(&deg[dst], 1);
}

__global__ __launch_bounds__(256) void k_scan(const int* __restrict__ deg, int* rowp,
                                              int* cursor, float* dinv) {
    __shared__ int part[256];
    int t = threadIdx.x, base = t * 8;
    int loc[8]; int s = 0;
    #pragma unroll
    for (int k = 0; k < 8; ++k) {
        int d = deg[base + k];
        int p = (d + 15) & ~15;
        loc[k] = p; s += p;
    }
    part[t] = s; __syncthreads();
    for (int off = 1; off < 256; off <<= 1) {
        int v = (t >= off) ? part[t - off] : 0;
        __syncthreads();
        part[t] += v;
        __syncthreads();
    }
    int run = part[t] - s;
    #pragma unroll
    for (int k = 0; k < 8; ++k) {
        rowp[base + k] = run; cursor[base + k] = run;
        int d = deg[base + k];
        dinv[base + k] = (d > 0) ? rsqrtf((float)d) : 0.f;
        run += loc[k];
    }
    if (t == 255) rowp[PITCH] = part[255];
}

__global__ void k_scatter(const void* eidx, const int* __restrict__ modes,
                          int* cursor, unsigned short* desc) {
    int idx = blockIdx.x * 256 + threadIdx.x;
    if (idx >= EPG + NNODE) return;
    int imode = modes[1];
    int s, d;
    if (idx < EPG) { s = ld_idx(eidx, idx, imode); d = ld_idx(eidx, (long)EPG + idx, imode); }
    else           { s = idx - EPG; d = s; }
    int pos = atomicAdd(&cursor[d], 1);
    desc[pos] = (unsigned short)s;
}

__global__ void k_convert(WPtrs wp, float* wf, const int* __restrict__ modes) {
    int idx = blockIdx.x * 256 + threadIdx.x;
    if (idx >= WFTOT) return;
    int fmode = modes[0];
    const int offs[10]  = {W0OFF,B0OFF,W1OFF,B1OFF,W2OFF,B2OFF,W3OFF,B3OFF,W4OFF,B4OFF};
    const int sizes[10] = {64,64,4096,64,4096,64,4096,64,64,1};
    #pragma unroll
    for (int s = 0; s < 10; ++s) {
        if (idx >= offs[s] && idx < offs[s] + sizes[s]) {
            int j = idx - offs[s];
            wf[idx] = fmode ? __bfloat162float(((const __hip_bfloat16*)wp.p[s])[j])
                            : ((const float*)wp.p[s])[j];
        }
    }
}

__global__ void k_mkfrag(const float* __restrict__ wf, short8* frag) {
    int t = blockIdx.x * 256 + threadIdx.x;
    if (t >= 3072) return;
    int lane = t & 63, half = (t >> 6) & 1, kh = (t >> 7) & 1, nb = (t >> 8) & 3, mat = t >> 10;
    const int woffs[3] = {W1OFF, W2OFF, W3OFF};
    const float* W = wf + woffs[mat];
    int n  = nb * 16 + (lane & 15);
    int k0 = kh * 32 + (lane >> 4) * 8;
    short8 v;
    #pragma unroll
    for (int j = 0; j < 8; ++j) {
        float w = W[(k0 + j) * 64 + n];
        unsigned short h = f2bf(w);
        v[j] = half ? (short)f2bf(w - bf2f(h)) : (short)h;
    }
    frag[t] = v;
}

// also zeroes the barrier counters (relocated into the dead cursor region)
__global__ void k_finalize(const float* __restrict__ dinv, const void* x,
                           const int* __restrict__ modes, unsigned* bars,
                           float* yin, float* yb, float* s4, void* out) {
    int idx = blockIdx.x * 256 + threadIdx.x;
    if (idx < 512) bars[idx] = 0u;
    if (idx >= NG * PITCH) return;
    int g = idx >> 11, local = idx & (PITCH - 1);
    if (local >= NNODE) { yin[idx] = 0.f; yb[idx] = 0.f; s4[idx] = 0.f; return; }
    int cn = g * NNODE + local;
    float y0 = modes[0] ? __bfloat162float(((const __hip_bfloat16*)x)[cn * TSTEPS + (TSTEPS - 1)])
                        : ((const float*)x)[cn * TSTEPS + (TSTEPS - 1)];
    yin[idx] = dinv[local] * y0;
    yb[idx]  = y0;
    if (modes[0]) ((__hip_bfloat16*)out)[cn * HOR] = __float2bfloat16(y0);
    else          ((float*)out)[cn * HOR] = y0;
}

// ---- heavy gather: dwordx4 rows, 32-edge unroll, packed f32x2 accumulators.
// R3-proven version (plain loads; freshness via barrier-exit buffer_inv sc0). ----
__device__ __forceinline__ void acc8(uint4 v, f32x2& a01, f32x2& a23,
                                     f32x2& a45, f32x2& a67) {
    a01 += unpk(v.x);
    a23 += unpk(v.y);
    a45 += unpk(v.z);
    a67 += unpk(v.w);
}

__device__ __forceinline__ void gather_tile(
        const uint4* __restrict__ hg128, const unsigned short* __restrict__ desc,
        const int* __restrict__ rowp, const float* __restrict__ dinv,
        int tb, int lane, int wv, float* tile, float* dinvt) {
    int fp3 = lane & 7, p8 = lane >> 3;
    #pragma unroll
    for (int r = 0; r < 4; ++r) {
        int m = (wv << 2) + r;
        int local = tb + m;
        int s = rowp[local], e = rowp[local + 1];   // multiples of 16
        f32x2 a01 = {0.f, 0.f}, a23 = {0.f, 0.f}, a45 = {0.f, 0.f}, a67 = {0.f, 0.f};
        int i = s;
        for (; i + 32 <= e; i += 32) {
            unsigned e0 = desc[i + p8];
            unsigned e1 = desc[i + 8 + p8];
            unsigned e2 = desc[i + 16 + p8];
            unsigned e3 = desc[i + 24 + p8];
            uint4 v0 = hg128[(e0 << 3) + fp3];
            uint4 v1 = hg128[(e1 << 3) + fp3];
            uint4 v2 = hg128[(e2 << 3) + fp3];
            uint4 v3 = hg128[(e3 << 3) + fp3];
            acc8(v0, a01, a23, a45, a67);
            acc8(v1, a01, a23, a45, a67);
            acc8(v2, a01, a23, a45, a67);
            acc8(v3, a01, a23, a45, a67);
        }
        if (i < e) {
            unsigned e0 = desc[i + p8];
            unsigned e1 = desc[i + 8 + p8];
            uint4 v0 = hg128[(e0 << 3) + fp3];
            uint4 v1 = hg128[(e1 << 3) + fp3];
            acc8(v0, a01, a23, a45, a67);
            acc8(v1, a01, a23, a45, a67);
        }
        float dv = dinv[local];
        f32x2 dv2 = {dv, dv};
        a01 *= dv2; a23 *= dv2; a45 *= dv2; a67 *= dv2;
        float a0 = a01.x, a1 = a01.y, a2 = a23.x, a3 = a23.y;
        float a4 = a45.x, a5 = a45.y, a6 = a67.x, a7 = a67.y;
        a0 += __shfl_xor(a0, 8); a0 += __shfl_xor(a0, 16); a0 += __shfl_xor(a0, 32);
        a1 += __shfl_xor(a1, 8); a1 += __shfl_xor(a1, 16); a1 += __shfl_xor(a1, 32);
        a2 += __shfl_xor(a2, 8); a2 += __shfl_xor(a2, 16); a2 += __shfl_xor(a2, 32);
        a3 += __shfl_xor(a3, 8); a3 += __shfl_xor(a3, 16); a3 += __shfl_xor(a3, 32);
        a4 += __shfl_xor(a4, 8); a4 += __shfl_xor(a4, 16); a4 += __shfl_xor(a4, 32);
        a5 += __shfl_xor(a5, 8); a5 += __shfl_xor(a5, 16); a5 += __shfl_xor(a5, 32);
        a6 += __shfl_xor(a6, 8); a6 += __shfl_xor(a6, 16); a6 += __shfl_xor(a6, 32);
        a7 += __shfl_xor(a7, 8); a7 += __shfl_xor(a7, 16); a7 += __shfl_xor(a7, 32);
        if (p8 == 0) {
            float4* dst = (float4*)&tile[m * 68 + (fp3 << 3)];
            dst[0] = make_float4(a0, a1, a2, a3);
            dst[1] = make_float4(a4, a5, a6, a7);
        }
        if (lane == 0) dinvt[m] = dv;
    }
}

__device__ __forceinline__ f32x4 transform_tile(
        const float* tile, const short8* __restrict__ fb,
        const float* __restrict__ wf, int boff, int lane, int wv) {
    short8 Bh0 = fb[(wv << 8) +   0 + lane];
    short8 Bl0 = fb[(wv << 8) +  64 + lane];
    short8 Bh1 = fb[(wv << 8) + 128 + lane];
    short8 Bl1 = fb[(wv << 8) + 192 + lane];
    int mrow = lane & 15, quad = lane >> 4;
    const float* arow = &tile[mrow * 68];
    float4 a0 = *(const float4*)(arow + (quad << 3));
    float4 a1 = *(const float4*)(arow + (quad << 3) + 4);
    float4 a2 = *(const float4*)(arow + 32 + (quad << 3));
    float4 a3 = *(const float4*)(arow + 32 + (quad << 3) + 4);
    float av0[8] = {a0.x, a0.y, a0.z, a0.w, a1.x, a1.y, a1.z, a1.w};
    float av1[8] = {a2.x, a2.y, a2.z, a2.w, a3.x, a3.y, a3.z, a3.w};
    short8 Ah0, Al0, Ah1, Al1;
    #pragma unroll
    for (int j = 0; j < 8; ++j) {
        unsigned short h0 = f2bf(av0[j]);
        Ah0[j] = (short)h0; Al0[j] = (short)f2bf(av0[j] - bf2f(h0));
        unsigned short h1 = f2bf(av1[j]);
        Ah1[j] = (short)h1; Al1[j] = (short)f2bf(av1[j] - bf2f(h1));
    }
    float bias = wf[boff + (wv << 4) + mrow];
    f32x4 c = {bias, bias, bias, bias};
    c = __builtin_amdgcn_mfma_f32_16x16x32_bf16(Ah0, Bh0, c, 0, 0, 0);
    c = __builtin_amdgcn_mfma_f32_16x16x32_bf16(Al0, Bh0, c, 0, 0, 0);
    c = __builtin_amdgcn_mfma_f32_16x16x32_bf16(Ah0, Bl0, c, 0, 0, 0);
    c = __builtin_amdgcn_mfma_f32_16x16x32_bf16(Ah1, Bh1, c, 0, 0, 0);
    c = __builtin_amdgcn_mfma_f32_16x16x32_bf16(Al1, Bh1, c, 0, 0, 0);
    c = __builtin_amdgcn_mfma_f32_16x16x32_bf16(Ah1, Bl1, c, 0, 0, 0);
    return c;
}

// ================= persistent ODE kernel =================
// R3 proved: one-XCD-per-graph mapping; plain stores + barrier-exit L1-inv is a
// correct intra-XCD coherence protocol. R4 proved sc0 loads are NOT a safe L1
// bypass. This round keeps the R3 data protocol verbatim and changes ONLY the
// barrier counter ops: arrival/poll become plain (no sc1) atomics that execute
// in the LOCAL TCC, eliminating the far-point (L3) round trips and the
// same-address serialization that cost ~18us/barrier in R3.

struct OdeArgs {
    unsigned short* hA; unsigned short* hB;
    float* yin; float* yb; float* kA; float* kB; float* kC; float* s4;
    const unsigned short* desc; const int* rowp; const float* dinv;
    const float* wf; const short8* frag;
    unsigned* bars; const int* modes; void* out;
};

__global__ __launch_bounds__(256, 4) void k_ode(OdeArgs A) {
    __shared__ float tile[16 * 68];
    __shared__ float dinvt[16];
    __shared__ float pd[4][16];
    __shared__ int sdead;
    __shared__ int sfast;

    const int b = blockIdx.x;
    const int g = b & 7, tb = (b >> 3) << 4;
    const int lane = threadIdx.x & 63, wv = threadIdx.x >> 6;
    const int fmode = A.modes[0];

    const unsigned short* __restrict__ desc = A.desc;
    const int* __restrict__ rowp = A.rowp;
    const float* __restrict__ dinvp = A.dinv;
    const float* __restrict__ wf = A.wf;
    const short8* __restrict__ frag = A.frag;
    unsigned* bar  = A.bars + (g << 6);   // 256B-separated per-graph counters
    unsigned* xccm = A.bars + 480 + g;    // per-graph XCC-mask
    unsigned* dead = A.bars + 509;        // global abort flag
    unsigned epoch = 0;

    // report this block's XCD (device-scope atomic; published by first slow barrier)
    if (threadIdx.x == 0) {
        unsigned xcc;
        asm volatile("s_getreg_b32 %0, hwreg(HW_REG_XCC_ID, 0, 4)" : "=s"(xcc));
        atomicOr(xccm, 1u << (xcc & 15u));
    }

    // per-graph arrive-and-wait barrier (monotone counter, no reset)
    auto gbar = [&](bool fast) -> bool {
        __syncthreads();                       // drains vmcnt for every wave
        ++epoch;
        if (threadIdx.x == 0) {
            const unsigned tgt = epoch * (unsigned)TILES;
            if (fast) {
                // local-TCC arrival: plain atomic (no sc bits) stays in this
                // XCD's L2 — no fabric round trip, no far-point serialization
                asm volatile("s_waitcnt vmcnt(0)" ::: "memory");
                asm volatile("global_atomic_add %0, %1, off"
                             :: "v"(U64(bar)), "v"(1u) : "memory");
            } else {
                // agent release: cross-XCD safe (slow)
                __hip_atomic_fetch_add(bar, 1u, __ATOMIC_RELEASE, __HIP_MEMORY_SCOPE_AGENT);
            }
            unsigned it = 0; int ok = 1;
            for (;;) {
                unsigned v;
                if (fast) {
                    // poll = atomic add-0 returning old: architecturally
                    // L1-bypassing, executes in the local TCC (L2-fresh read)
                    asm volatile("global_atomic_add %0, %1, %2, off sc0\n\t"
                                 "s_waitcnt vmcnt(0)"
                                 : "=&v"(v) : "v"(U64(bar)), "v"(0u) : "memory");
                } else {
                    v = __hip_atomic_load(bar, __ATOMIC_RELAXED, __HIP_MEMORY_SCOPE_AGENT);
                }
                if (v >= tgt) break;
                __builtin_amdgcn_s_sleep(2);
                if ((++it & 2047u) == 0u) {
                    if (it > 2000000u ||
                        __hip_atomic_load(dead, __ATOMIC_RELAXED, __HIP_MEMORY_SCOPE_AGENT) != 0u) {
                        __hip_atomic_store(dead, 1u, __ATOMIC_RELAXED, __HIP_MEMORY_SCOPE_AGENT);
                        ok = 0; break;
                    }
                }
            }
            if (fast) {
                // L1-only invalidate (per-CU); fresh data comes from shared L2
                asm volatile("buffer_inv sc0\n\ts_waitcnt vmcnt(0)" ::: "memory");
            } else {
                __threadfence();               // agent acquire (slow path only)
            }
            sdead = ok ? 0 : 1;
        }
        __syncthreads();
        return sdead == 0;
    };

    auto do_layer0 = [&]() {                   // scalar gather -> 64-wide h, writes hA
        const float* yg = A.yin + g * PITCH;
        int grp = lane >> 4, j = lane & 15;
        int local = tb + (wv << 2) + grp;
        int s = rowp[local], e = rowp[local + 1];
        float acc = 0.f;
        for (int i = s + j; i < e; i += 16) acc += yg[desc[i]];
        acc += __shfl_xor(acc, 1); acc += __shfl_xor(acc, 2);
        acc += __shfl_xor(acc, 4); acc += __shfl_xor(acc, 8);
        float w0 = wf[W0OFF + lane], b0 = wf[B0OFF + lane];
        #pragma unroll
        for (int r = 0; r < 4; ++r) {
            float Z = __shfl(acc, r << 4);
            int ln = tb + (wv << 2) + r;
            float dv = dinvp[ln];
            float o = dv * tanh_fast(dv * Z * w0 + b0);
            A.hA[((size_t)(g * PITCH + ln) << 6) + lane] = f2bf(o);
        }
    };

    auto do_heavy = [&](const unsigned short* hin, unsigned short* hout,
                        int mat, int boff) {
        const uint4* hg128 = (const uint4*)(hin + ((size_t)g * PITCH << 6));
        gather_tile(hg128, desc, rowp, dinvp, tb, lane, wv, tile, dinvt);
        __syncthreads();
        f32x4 c = transform_tile(tile, frag + (mat << 10), wf, boff, lane, wv);
        int mrow = lane & 15, quad = lane >> 4;
        #pragma unroll
        for (int r = 0; r < 4; ++r) {
            int m = (quad << 2) + r;
            hout[(((size_t)g * PITCH + tb + m) << 6) + (wv << 4) + mrow] =
                f2bf(dinvt[m] * tanh_fast(c[r]));
        }
    };

    auto do_heavy_fuse = [&](const unsigned short* hin, int mat, int boff) {
        const uint4* hg128 = (const uint4*)(hin + ((size_t)g * PITCH << 6));
        gather_tile(hg128, desc, rowp, dinvp, tb, lane, wv, tile, dinvt);
        __syncthreads();
        f32x4 c = transform_tile(tile, frag + (mat << 10), wf, boff, lane, wv);
        int mrow = lane & 15, quad = lane >> 4;
        float w4v = wf[W4OFF + (wv << 4) + mrow];
        #pragma unroll
        for (int r = 0; r < 4; ++r) {
            float d = tanh_fast(c[r]) * w4v;
            d += __shfl_xor(d, 1); d += __shfl_xor(d, 2);
            d += __shfl_xor(d, 4); d += __shfl_xor(d, 8);
            if (mrow == 0) pd[wv][(quad << 2) + r] = d;
        }
        __syncthreads();
        if (threadIdx.x < 16)
            A.s4[g * PITCH + tb + threadIdx.x] = dinvt[threadIdx.x] *
                (pd[0][threadIdx.x] + pd[1][threadIdx.x] + pd[2][threadIdx.x] + pd[3][threadIdx.x]);
    };

    auto do_prop = [&](float c1, float c2, float c3, float c4, int stage, int hidx) {
        const float* sg = A.s4 + g * PITCH;
        int grp = lane >> 4, j = lane & 15;
        int local = tb + (wv << 2) + grp;
        int s = rowp[local], e = rowp[local + 1];
        float acc = 0.f;
        for (int i = s + j; i < e; i += 16) acc += sg[desc[i]];
        acc += __shfl_xor(acc, 1); acc += __shfl_xor(acc, 2);
        acc += __shfl_xor(acc, 4); acc += __shfl_xor(acc, 8);
        if (j == 0) {
            int idx = g * PITCH + local;
            float dv = dinvp[local];
            float k = dv * acc + wf[B4OFF];
            float ynew = A.yb[idx] + c1 * A.kA[idx] + c2 * A.kB[idx] + c3 * A.kC[idx] + c4 * k;
            if (stage == 0) A.kA[idx] = k;
            else if (stage == 1) A.kB[idx] = k;
            else if (stage == 2) A.kC[idx] = k;
            A.yin[idx] = dv * ynew;
            if (stage == 3) {
                A.yb[idx] = ynew;
                int cn = g * NNODE + local;
                if (fmode) ((__hip_bfloat16*)A.out)[cn * HOR + hidx] = __float2bfloat16(ynew);
                else       ((float*)A.out)[cn * HOR + hidx] = ynew;
            }
        }
    };

    const float dt = 10.f / 9.f, dt3 = dt / 3.f;

    do_layer0();
    if (!gbar(false)) return;                  // slow barrier #1 publishes xccm

    if (threadIdx.x == 0) {
        unsigned m = __hip_atomic_load(xccm, __ATOMIC_RELAXED, __HIP_MEMORY_SCOPE_AGENT);
        sfast = (__popc(m) == 1) ? 1 : 0;      // all 125 blocks on one XCD?
    }
    __syncthreads();
    const bool fast = (sfast != 0);

    for (int it = 0; it < 4 * NSTEP; ++it) {
        int st = it & 3, step = it >> 2;
        float c1 = (st == 1) ? -dt3 : (st == 2) ? dt : (st == 3) ? dt * 0.125f : 0.f;
        float c2 = (st == 2) ? -dt  : (st == 3) ? dt * 0.375f : 0.f;
        float c3 = (st == 3) ? dt * 0.375f : 0.f;
        float c4 = (st == 0) ? dt3  : (st == 3) ? dt * 0.125f : dt;

        do_heavy(A.hA, A.hB, 0, B1OFF); if (!gbar(fast)) return;
        do_heavy(A.hB, A.hA, 1, B2OFF); if (!gbar(fast)) return;
        do_heavy_fuse(A.hA, 2, B3OFF);  if (!gbar(fast)) return;
        do_prop(c1, c2, c3, c4, st, step + 1); if (!gbar(fast)) return;
        if (it != 4 * NSTEP - 1) { do_layer0(); if (!gbar(fast)) return; }
    }
}

// ================= host =================

extern "C" void kernel_launch(void* const* d_in, const int* in_sizes, int n_in,
                              void* d_out, int out_size, void* d_ws, size_t ws_size,
                              hipStream_t stream) {
    char* ws = (char*)d_ws;
    unsigned short* desc = (unsigned short*)(ws + OFF_DESC);
    unsigned short* hA   = (unsigned short*)(ws + OFF_HA);
    unsigned short* hB   = (unsigned short*)(ws + OFF_HB);
    float* yin  = (float*)(ws + OFF_YIN);
    float* yb   = (float*)(ws + OFF_YB);
    float* kA   = (float*)(ws + OFF_KA);
    float* kB   = (float*)(ws + OFF_KB);
    float* kC   = (float*)(ws + OFF_KC);
    float* s4   = (float*)(ws + OFF_S4);
    int*   deg  = (int*)(ws + OFF_DEG);
    int*   cur  = (int*)(ws + OFF_CUR);
    int*   rowp = (int*)(ws + OFF_ROWP);
    float* dinv = (float*)(ws + OFF_DINV);
    int*   modes= (int*)(ws + OFF_MODES);
    float* wf   = (float*)(ws + OFF_WF);
    short8* wfrag = (short8*)(ws + OFF_WFRAG);
    unsigned* bars = (unsigned*)(ws + OFF_CUR);   // cursor region reused post-scatter

    const void* x    = d_in[0];
    const void* eidx = d_in[1];
    WPtrs wp;
    for (int i = 0; i < 10; ++i) wp.p[i] = d_in[2 + i];

    k_detect  <<<1, 64, 0, stream>>>(x, eidx, modes);
    k_setup0  <<<192, 256, 0, stream>>>(deg, (unsigned*)desc, (unsigned*)hA, (unsigned*)hB);
    k_count   <<<EPG / 256, 256, 0, stream>>>(eidx, modes, deg);
    k_scan    <<<1, 256, 0, stream>>>(deg, rowp, cur, dinv);
    k_scatter <<<(EPG + NNODE + 255) / 256, 256, 0, stream>>>(eidx, modes, cur, desc);
    k_convert <<<(WFTOT + 255) / 256, 256, 0, stream>>>(wp, wf, modes);
    k_mkfrag  <<<12, 256, 0, stream>>>(wf, wfrag);
    k_finalize<<<NG * PITCH / 256, 256, 0, stream>>>(dinv, x, modes, bars, yin, yb, s4, d_out);

    OdeArgs a;
    a.hA = hA; a.hB = hB; a.yin = yin; a.yb = yb; a.kA = kA; a.kB = kB; a.kC = kC;
    a.s4 = s4; a.desc = desc; a.rowp = rowp; a.dinv = dinv; a.wf = wf;
    a.frag = wfrag; a.bars = bars; a.modes = modes; a.out = d_out;
    k_ode<<<dim3(NG * TILES), dim3(256), 0, stream>>>(a);
}

// Round 6
// 1395.241 us; speedup vs baseline: 6.9447x; 2.3788x over previous
//
#include <hip/hip_runtime.h>
#include <hip/hip_bf16.h>

#define NNODE   2000
#define NG      8
#define EPG     64000
#define TSTEPS  24
#define HOR     10
#define NSTEP   (HOR-1)
#define PITCH   2048          // per-graph node pitch; row 2047 is the zero row
#define ECAP    98304         // padded CSR capacity (ushorts)
#define TILES   125           // 2000 / 16

// ---- workspace layout (bytes) ----
#define OFF_DESC    0
#define OFF_HA      196608
#define OFF_HB      2293760
#define OFF_YIN     4390912
#define OFF_YB      4456448
#define OFF_KA      4521984
#define OFF_KB      4587520
#define OFF_KC      4653056
#define OFF_S4      4718592
#define OFF_DEG     4784128
#define OFF_CUR     4792320
#define OFF_ROWP    4800512
#define OFF_DINV    4808960
#define OFF_MODES   4817152
#define OFF_WF      4817408
#define OFF_WFRAG   4868352
// total ~4.92 MB

#define W0OFF 0
#define B0OFF 64
#define W1OFF 128
#define B1OFF 4224
#define W2OFF 4288
#define B2OFF 8384
#define W3OFF 8448
#define B3OFF 12544
#define W4OFF 12608
#define B4OFF 12672
#define WFTOT 12673

typedef __attribute__((ext_vector_type(8))) short short8;
typedef __attribute__((ext_vector_type(4))) float f32x4;
typedef __attribute__((ext_vector_type(2))) float f32x2;

struct WPtrs { const void* p[10]; };

__device__ inline float tanh_fast(float x) {
    float xc = fminf(fmaxf(x, -15.f), 15.f);
    float e  = __expf(2.f * xc);
    return 1.f - 2.f / (e + 1.f);
}
__device__ inline unsigned short f2bf(float f) {
    unsigned u = __float_as_uint(f);
    u += 0x7fff + ((u >> 16) & 1);
    return (unsigned short)(u >> 16);
}
__device__ inline float bf2f(unsigned short h) {
    return __uint_as_float(((unsigned)h) << 16);
}
__device__ inline int ld_idx(const void* p, long i, int imode) {
    return imode ? (int)((const long long*)p)[i] : ((const int*)p)[i];
}

// unpack one dword (2 bf16 feats) into a register-pair float2 -> feeds v_pk_add_f32
__device__ inline f32x2 unpk(unsigned v) {
    f32x2 r;
    r.x = __uint_as_float(v << 16);
    r.y = __uint_as_float(v & 0xffff0000u);
    return r;
}

// ================= setup kernels =================

__global__ void k_detect(const void* x, const void* eidx, int* modes) {
    int lane = threadIdx.x;
    const unsigned* xw = (const unsigned*)x;
    unsigned w = xw[lane];
    int ex = (w >> 7) & 0xFF;
    unsigned long long m = __ballot(ex >= 100 && ex <= 145);
    const unsigned* ew = (const unsigned*)eidx;
    unsigned long long m2 = __ballot(ew[2*lane + 1] != 0);
    if (lane == 0) {
        modes[0] = (__popcll(m) >= 48) ? 1 : 0;
        modes[1] = (__popcll(m2) == 0) ? 1 : 0;
    }
}

// merged: deg init + desc sentinel fill + h pad-row zeroing
__global__ void k_setup0(int* deg, unsigned* desc32, unsigned* hA32, unsigned* hB32) {
    int n = blockIdx.x * 256 + threadIdx.x;
    if (n < PITCH) deg[n] = (n < NNODE) ? 1 : 0;
    if (n < ECAP / 2) desc32[n] = 0x07FF07FFu;     // sentinel -> zero row 2047
    if (n < 2 * NG * 48 * 32) {
        int b = n / (NG * 48 * 32), r = n % (NG * 48 * 32);
        int g = r / (48 * 32), rr = r % (48 * 32);
        int row = NNODE + rr / 32, fp = rr % 32;
        unsigned* pp = b ? hB32 : hA32;
        pp[(g * PITCH + row) * 32 + fp] = 0;
    }
}

__global__ void k_count(const void* eidx, const int* __restrict__ modes, int* deg) {
    int e = blockIdx.x * 256 + threadIdx.x;
    int imode = modes[1];
    int dst = ld_idx(eidx, (long)EPG + e, imode);
    atomicAdd(&deg[dst], 1);
}

// pad rows to 8 (was 16): padded slots read the zero row -> pure zero-adds;
// per-lane accumulation order (positions == p8 mod 8, increasing) unchanged.
__global__ __launch_bounds__(256) void k_scan(const int* __restrict__ deg, int* rowp,
                                              int* cursor, float* dinv) {
    __shared__ int part[256];
    int t = threadIdx.x, base = t * 8;
    int loc[8]; int s = 0;
    #pragma unroll
    for (int k = 0; k < 8; ++k) {
        int d = deg[base + k];
        int p = (d + 7) & ~7;
        loc[k] = p; s += p;
    }
    part[t] = s; __syncthreads();
    for (int off = 1; off < 256; off <<= 1) {
        int v = (t >= off) ? part[t - off] : 0;
        __syncthreads();
        part[t] += v;
        __syncthreads();
    }
    int run = part[t] - s;
    #pragma unroll
    for (int k = 0; k < 8; ++k) {
        rowp[base + k] = run; cursor[base + k] = run;
        int d = deg[base + k];
        dinv[base + k] = (d > 0) ? rsqrtf((float)d) : 0.f;
        run += loc[k];
    }
    if (t == 255) rowp[PITCH] = part[255];
}

__global__ void k_scatter(const void* eidx, const int* __restrict__ modes,
                          int* cursor, unsigned short* desc) {
    int idx = blockIdx.x * 256 + threadIdx.x;
    if (idx >= EPG + NNODE) return;
    int imode = modes[1];
    int s, d;
    if (idx < EPG) { s = ld_idx(eidx, idx, imode); d = ld_idx(eidx, (long)EPG + idx, imode); }
    else           { s = idx - EPG; d = s; }
    int pos = atomicAdd(&cursor[d], 1);
    desc[pos] = (unsigned short)s;
}

__global__ void k_convert(WPtrs wp, float* wf, const int* __restrict__ modes) {
    int idx = blockIdx.x * 256 + threadIdx.x;
    if (idx >= WFTOT) return;
    int fmode = modes[0];
    const int offs[10]  = {W0OFF,B0OFF,W1OFF,B1OFF,W2OFF,B2OFF,W3OFF,B3OFF,W4OFF,B4OFF};
    const int sizes[10] = {64,64,4096,64,4096,64,4096,64,64,1};
    #pragma unroll
    for (int s = 0; s < 10; ++s) {
        if (idx >= offs[s] && idx < offs[s] + sizes[s]) {
            int j = idx - offs[s];
            wf[idx] = fmode ? __bfloat162float(((const __hip_bfloat16*)wp.p[s])[j])
                            : ((const float*)wp.p[s])[j];
        }
    }
}

__global__ void k_mkfrag(const float* __restrict__ wf, short8* frag) {
    int t = blockIdx.x * 256 + threadIdx.x;
    if (t >= 3072) return;
    int lane = t & 63, half = (t >> 6) & 1, kh = (t >> 7) & 1, nb = (t >> 8) & 3, mat = t >> 10;
    const int woffs[3] = {W1OFF, W2OFF, W3OFF};
    const float* W = wf + woffs[mat];
    int n  = nb * 16 + (lane & 15);
    int k0 = kh * 32 + (lane >> 4) * 8;
    short8 v;
    #pragma unroll
    for (int j = 0; j < 8; ++j) {
        float w = W[(k0 + j) * 64 + n];
        unsigned short h = f2bf(w);
        v[j] = half ? (short)f2bf(w - bf2f(h)) : (short)h;
    }
    frag[t] = v;
}

__global__ void k_finalize(const float* __restrict__ dinv, const void* x,
                           const int* __restrict__ modes,
                           float* yin, float* yb, float* s4, void* out) {
    int idx = blockIdx.x * 256 + threadIdx.x;
    if (idx >= NG * PITCH) return;
    int g = idx >> 11, local = idx & (PITCH - 1);
    if (local >= NNODE) { yin[idx] = 0.f; yb[idx] = 0.f; s4[idx] = 0.f; return; }
    int cn = g * NNODE + local;
    float y0 = modes[0] ? __bfloat162float(((const __hip_bfloat16*)x)[cn * TSTEPS + (TSTEPS - 1)])
                        : ((const float*)x)[cn * TSTEPS + (TSTEPS - 1)];
    yin[idx] = dinv[local] * y0;
    yb[idx]  = y0;
    if (modes[0]) ((__hip_bfloat16*)out)[cn * HOR] = __float2bfloat16(y0);
    else          ((float*)out)[cn * HOR] = y0;
}

// ---- layer 0: 16 lanes per node, 4 nodes/wave, tile/block, grid 1000 ----
// stride-16 loop naturally handles 8-padded rows (lanes j>=8 skip short tails)
__global__ __launch_bounds__(256) void k_layer0(
        const float* __restrict__ yin, unsigned short* __restrict__ hout,
        const unsigned short* __restrict__ desc, const int* __restrict__ rowp,
        const float* __restrict__ dinv, const float* __restrict__ wf) {
    int lane = threadIdx.x & 63, wv = threadIdx.x >> 6;
    int b = blockIdx.x;
    int g = b & 7, tb = (b >> 3) << 4;
    const float* yg = yin + g * PITCH;
    int grp = lane >> 4, j = lane & 15;
    int local = tb + (wv << 2) + grp;
    int s = rowp[local], e = rowp[local + 1];
    float acc = 0.f;
    for (int i = s + j; i < e; i += 16) acc += yg[desc[i]];
    acc += __shfl_xor(acc, 1); acc += __shfl_xor(acc, 2);
    acc += __shfl_xor(acc, 4); acc += __shfl_xor(acc, 8);
    float w0 = wf[W0OFF + lane], b0 = wf[B0OFF + lane];
    #pragma unroll
    for (int r = 0; r < 4; ++r) {
        float Z = __shfl(acc, r << 4);
        int ln = tb + (wv << 2) + r;
        float dv = dinv[ln];
        float o = dv * tanh_fast(dv * Z * w0 + b0);
        hout[((size_t)(g * PITCH + ln) << 6) + lane] = f2bf(o);
    }
}

// ---- heavy gather: dwordx4 rows, 32-edge unroll + 16/8 tails, packed f32x2 acc.
// Rows are multiples of 8 now; per-lane accumulation order preserved. ----
__device__ __forceinline__ void acc8(uint4 v, f32x2& a01, f32x2& a23,
                                     f32x2& a45, f32x2& a67) {
    a01 += unpk(v.x);
    a23 += unpk(v.y);
    a45 += unpk(v.z);
    a67 += unpk(v.w);
}

__device__ __forceinline__ void gather_tile(
        const uint4* __restrict__ hg128, const unsigned short* __restrict__ desc,
        const int* __restrict__ rowp, const float* __restrict__ dinv,
        int tb, int lane, int wv, float* tile, float* dinvt) {
    int fp3 = lane & 7, p8 = lane >> 3;
    #pragma unroll
    for (int r = 0; r < 4; ++r) {
        int m = (wv << 2) + r;
        int local = tb + m;
        int s = rowp[local], e = rowp[local + 1];   // multiples of 8
        f32x2 a01 = {0.f, 0.f}, a23 = {0.f, 0.f}, a45 = {0.f, 0.f}, a67 = {0.f, 0.f};
        int i = s;
        for (; i + 32 <= e; i += 32) {
            unsigned e0 = desc[i + p8];
            unsigned e1 = desc[i + 8 + p8];
            unsigned e2 = desc[i + 16 + p8];
            unsigned e3 = desc[i + 24 + p8];
            uint4 v0 = hg128[(e0 << 3) + fp3];
            uint4 v1 = hg128[(e1 << 3) + fp3];
            uint4 v2 = hg128[(e2 << 3) + fp3];
            uint4 v3 = hg128[(e3 << 3) + fp3];
            acc8(v0, a01, a23, a45, a67);
            acc8(v1, a01, a23, a45, a67);
            acc8(v2, a01, a23, a45, a67);
            acc8(v3, a01, a23, a45, a67);
        }
        if (i + 16 <= e) {
            unsigned e0 = desc[i + p8];
            unsigned e1 = desc[i + 8 + p8];
            uint4 v0 = hg128[(e0 << 3) + fp3];
            uint4 v1 = hg128[(e1 << 3) + fp3];
            acc8(v0, a01, a23, a45, a67);
            acc8(v1, a01, a23, a45, a67);
            i += 16;
        }
        if (i < e) {                                // 8-edge tail (pad-8)
            unsigned e0 = desc[i + p8];
            uint4 v0 = hg128[(e0 << 3) + fp3];
            acc8(v0, a01, a23, a45, a67);
        }
        float dv = dinv[local];
        f32x2 dv2 = {dv, dv};
        a01 *= dv2; a23 *= dv2; a45 *= dv2; a67 *= dv2;
        float a0 = a01.x, a1 = a01.y, a2 = a23.x, a3 = a23.y;
        float a4 = a45.x, a5 = a45.y, a6 = a67.x, a7 = a67.y;
        a0 += __shfl_xor(a0, 8); a0 += __shfl_xor(a0, 16); a0 += __shfl_xor(a0, 32);
        a1 += __shfl_xor(a1, 8); a1 += __shfl_xor(a1, 16); a1 += __shfl_xor(a1, 32);
        a2 += __shfl_xor(a2, 8); a2 += __shfl_xor(a2, 16); a2 += __shfl_xor(a2, 32);
        a3 += __shfl_xor(a3, 8); a3 += __shfl_xor(a3, 16); a3 += __shfl_xor(a3, 32);
        a4 += __shfl_xor(a4, 8); a4 += __shfl_xor(a4, 16); a4 += __shfl_xor(a4, 32);
        a5 += __shfl_xor(a5, 8); a5 += __shfl_xor(a5, 16); a5 += __shfl_xor(a5, 32);
        a6 += __shfl_xor(a6, 8); a6 += __shfl_xor(a6, 16); a6 += __shfl_xor(a6, 32);
        a7 += __shfl_xor(a7, 8); a7 += __shfl_xor(a7, 16); a7 += __shfl_xor(a7, 32);
        if (p8 == 0) {
            float4* dst = (float4*)&tile[m * 68 + (fp3 << 3)];
            dst[0] = make_float4(a0, a1, a2, a3);
            dst[1] = make_float4(a4, a5, a6, a7);
        }
        if (lane == 0) dinvt[m] = dv;
    }
}

__device__ __forceinline__ f32x4 transform_tile(
        const float* tile, const short8* __restrict__ fb,
        const float* __restrict__ wf, int boff, int lane, int wv) {
    short8 Bh0 = fb[(wv << 8) +   0 + lane];
    short8 Bl0 = fb[(wv << 8) +  64 + lane];
    short8 Bh1 = fb[(wv << 8) + 128 + lane];
    short8 Bl1 = fb[(wv << 8) + 192 + lane];
    int mrow = lane & 15, quad = lane >> 4;
    const float* arow = &tile[mrow * 68];
    float4 a0 = *(const float4*)(arow + (quad << 3));
    float4 a1 = *(const float4*)(arow + (quad << 3) + 4);
    float4 a2 = *(const float4*)(arow + 32 + (quad << 3));
    float4 a3 = *(const float4*)(arow + 32 + (quad << 3) + 4);
    float av0[8] = {a0.x, a0.y, a0.z, a0.w, a1.x, a1.y, a1.z, a1.w};
    float av1[8] = {a2.x, a2.y, a2.z, a2.w, a3.x, a3.y, a3.z, a3.w};
    short8 Ah0, Al0, Ah1, Al1;
    #pragma unroll
    for (int j = 0; j < 8; ++j) {
        unsigned short h0 = f2bf(av0[j]);
        Ah0[j] = (short)h0; Al0[j] = (short)f2bf(av0[j] - bf2f(h0));
        unsigned short h1 = f2bf(av1[j]);
        Ah1[j] = (short)h1; Al1[j] = (short)f2bf(av1[j] - bf2f(h1));
    }
    float bias = wf[boff + (wv << 4) + mrow];
    f32x4 c = {bias, bias, bias, bias};
    c = __builtin_amdgcn_mfma_f32_16x16x32_bf16(Ah0, Bh0, c, 0, 0, 0);
    c = __builtin_amdgcn_mfma_f32_16x16x32_bf16(Al0, Bh0, c, 0, 0, 0);
    c = __builtin_amdgcn_mfma_f32_16x16x32_bf16(Ah0, Bl0, c, 0, 0, 0);
    c = __builtin_amdgcn_mfma_f32_16x16x32_bf16(Ah1, Bh1, c, 0, 0, 0);
    c = __builtin_amdgcn_mfma_f32_16x16x32_bf16(Al1, Bh1, c, 0, 0, 0);
    c = __builtin_amdgcn_mfma_f32_16x16x32_bf16(Ah1, Bl1, c, 0, 0, 0);
    return c;
}

// ---- heavy layers ----
template<int FUSE>
__global__ __launch_bounds__(256, 4) void k_layer(
        const unsigned short* __restrict__ hin, unsigned short* __restrict__ hout,
        float* __restrict__ s4,
        const unsigned short* __restrict__ desc, const int* __restrict__ rowp,
        const float* __restrict__ dinv, const float* __restrict__ wf,
        const short8* __restrict__ frag, int mat, int boff) {
    __shared__ float tile[16 * 68];
    __shared__ float dinvt[16];
    __shared__ float pd[4][16];
    int lane = threadIdx.x & 63, wv = threadIdx.x >> 6;
    int b = blockIdx.x;
    int g = b & 7, tb = (b >> 3) << 4;
    const uint4* hg128 = (const uint4*)(hin + ((size_t)g * PITCH << 6));

    gather_tile(hg128, desc, rowp, dinv, tb, lane, wv, tile, dinvt);
    __syncthreads();
    f32x4 c = transform_tile(tile, frag + (mat << 10), wf, boff, lane, wv);

    int mrow = lane & 15, quad = lane >> 4;
    if (!FUSE) {
        #pragma unroll
        for (int r = 0; r < 4; ++r) {
            int m = (quad << 2) + r;
            hout[(((size_t)g * PITCH + tb + m) << 6) + (wv << 4) + mrow] = f2bf(dinvt[m] * tanh_fast(c[r]));
        }
    } else {
        float w4v = wf[W4OFF + (wv << 4) + mrow];
        #pragma unroll
        for (int r = 0; r < 4; ++r) {
            float d = tanh_fast(c[r]) * w4v;
            d += __shfl_xor(d, 1); d += __shfl_xor(d, 2);
            d += __shfl_xor(d, 4); d += __shfl_xor(d, 8);
            if (mrow == 0) pd[wv][(quad << 2) + r] = d;
        }
        __syncthreads();
        if (threadIdx.x < 16)
            s4[g * PITCH + tb + threadIdx.x] = dinvt[threadIdx.x] *
                (pd[0][threadIdx.x] + pd[1][threadIdx.x] + pd[2][threadIdx.x] + pd[3][threadIdx.x]);
    }
}

// ---- prop: 16 lanes per node, 4 nodes/wave, grid 1000 ----
__global__ __launch_bounds__(256) void k_prop(
        const float* __restrict__ s4, const unsigned short* __restrict__ desc,
        const int* __restrict__ rowp, const float* __restrict__ dinv,
        const float* __restrict__ wf,
        float* yin, float* yb, float* kA, float* kB, float* kC,
        float c1, float c2, float c3, float c4, int stage,
        const int* __restrict__ modes, void* out, int hidx) {
    int lane = threadIdx.x & 63, wv = threadIdx.x >> 6;
    int b = blockIdx.x;
    int g = b & 7, tb = (b >> 3) << 4;
    const float* sg = s4 + g * PITCH;
    int grp = lane >> 4, j = lane & 15;
    int local = tb + (wv << 2) + grp;
    int s = rowp[local], e = rowp[local + 1];
    float acc = 0.f;
    for (int i = s + j; i < e; i += 16) acc += sg[desc[i]];
    acc += __shfl_xor(acc, 1); acc += __shfl_xor(acc, 2);
    acc += __shfl_xor(acc, 4); acc += __shfl_xor(acc, 8);
    if (j == 0) {
        int idx = g * PITCH + local;
        float dv = dinv[local];
        float k = dv * acc + wf[B4OFF];
        float ynew = yb[idx] + c1 * kA[idx] + c2 * kB[idx] + c3 * kC[idx] + c4 * k;
        if (stage == 0) kA[idx] = k;
        else if (stage == 1) kB[idx] = k;
        else if (stage == 2) kC[idx] = k;
        yin[idx] = dv * ynew;
        if (stage == 3) {
            yb[idx] = ynew;
            int cn = g * NNODE + local;
            if (modes[0]) ((__hip_bfloat16*)out)[cn * HOR + hidx] = __float2bfloat16(ynew);
            else          ((float*)out)[cn * HOR + hidx] = ynew;
        }
    }
}

// ================= host =================

extern "C" void kernel_launch(void* const* d_in, const int* in_sizes, int n_in,
                              void* d_out, int out_size, void* d_ws, size_t ws_size,
                              hipStream_t stream) {
    char* ws = (char*)d_ws;
    unsigned short* desc = (unsigned short*)(ws + OFF_DESC);
    unsigned short* hA   = (unsigned short*)(ws + OFF_HA);
    unsigned short* hB   = (unsigned short*)(ws + OFF_HB);
    float* yin  = (float*)(ws + OFF_YIN);
    float* yb   = (float*)(ws + OFF_YB);
    float* kA   = (float*)(ws + OFF_KA);
    float* kB   = (float*)(ws + OFF_KB);
    float* kC   = (float*)(ws + OFF_KC);
    float* s4   = (float*)(ws + OFF_S4);
    int*   deg  = (int*)(ws + OFF_DEG);
    int*   cur  = (int*)(ws + OFF_CUR);
    int*   rowp = (int*)(ws + OFF_ROWP);
    float* dinv = (float*)(ws + OFF_DINV);
    int*   modes= (int*)(ws + OFF_MODES);
    float* wf   = (float*)(ws + OFF_WF);
    short8* wfrag = (short8*)(ws + OFF_WFRAG);

    const void* x    = d_in[0];
    const void* eidx = d_in[1];
    WPtrs wp;
    for (int i = 0; i < 10; ++i) wp.p[i] = d_in[2 + i];

    k_detect  <<<1, 64, 0, stream>>>(x, eidx, modes);
    k_setup0  <<<192, 256, 0, stream>>>(deg, (unsigned*)desc, (unsigned*)hA, (unsigned*)hB);
    k_count   <<<EPG / 256, 256, 0, stream>>>(eidx, modes, deg);
    k_scan    <<<1, 256, 0, stream>>>(deg, rowp, cur, dinv);
    k_scatter <<<(EPG + NNODE + 255) / 256, 256, 0, stream>>>(eidx, modes, cur, desc);
    k_convert <<<(WFTOT + 255) / 256, 256, 0, stream>>>(wp, wf, modes);
    k_mkfrag  <<<12, 256, 0, stream>>>(wf, wfrag);
    k_finalize<<<NG * PITCH / 256, 256, 0, stream>>>(dinv, x, modes, yin, yb, s4, d_out);

    const float dt = 10.f / 9.f, dt3 = dt / 3.f;
    const float C1[4] = {0.f,  -dt3, dt,  dt * 0.125f};
    const float C2[4] = {0.f,  0.f,  -dt, dt * 0.375f};
    const float C3[4] = {0.f,  0.f,  0.f, dt * 0.375f};
    const float C4[4] = {dt3,  dt,   dt,  dt * 0.125f};

    k_layer0<<<1000, 256, 0, stream>>>(yin, hA, desc, rowp, dinv, wf);  // initial

    for (int step = 0; step < NSTEP; ++step) {
        for (int st = 0; st < 4; ++st) {
            k_layer<0><<<1000, 256, 0, stream>>>(hA, hB, nullptr, desc, rowp, dinv, wf, wfrag, 0, B1OFF);
            k_layer<0><<<1000, 256, 0, stream>>>(hB, hA, nullptr, desc, rowp, dinv, wf, wfrag, 1, B2OFF);
            k_layer<1><<<1000, 256, 0, stream>>>(hA, nullptr, s4, desc, rowp, dinv, wf, wfrag, 2, B3OFF);
            k_prop    <<<1000, 256, 0, stream>>>(s4, desc, rowp, dinv, wf, yin, yb, kA, kB, kC,
                                                 C1[st], C2[st], C3[st], C4[st], st,
                                                 modes, d_out, step + 1);
            if (step < NSTEP - 1 || st < 3)
                k_layer0<<<1000, 256, 0, stream>>>(yin, hA, desc, rowp, dinv, wf);
        }
    }
}

// Round 7
// 1330.527 us; speedup vs baseline: 7.2825x; 1.0486x over previous
//
#include <hip/hip_runtime.h>
#include <hip/hip_bf16.h>

#define NNODE   2000
#define NG      8
#define EPG     64000
#define TSTEPS  24
#define HOR     10
#define NSTEP   (HOR-1)
#define PITCH   2048          // per-graph node pitch; row 2047 is the zero row
#define ECAP    98304         // padded CSR capacity (ushorts)
#define TILES   125           // 2000 / 16

// ---- workspace layout (bytes) ----
#define OFF_DESC    0
#define OFF_HA      196608
#define OFF_HB      2293760
#define OFF_YIN     4390912
#define OFF_YB      4456448
#define OFF_KA      4521984
#define OFF_KB      4587520
#define OFF_KC      4653056
#define OFF_S4      4718592
#define OFF_DEG     4784128
#define OFF_CUR     4792320
#define OFF_ROWP    4800512
#define OFF_DINV    4808960
#define OFF_MODES   4817152
#define OFF_WF      4817408
#define OFF_WFRAG   4868352
// total ~4.92 MB

#define W0OFF 0
#define B0OFF 64
#define W1OFF 128
#define B1OFF 4224
#define W2OFF 4288
#define B2OFF 8384
#define W3OFF 8448
#define B3OFF 12544
#define W4OFF 12608
#define B4OFF 12672
#define WFTOT 12673

typedef __attribute__((ext_vector_type(8))) short short8;
typedef __attribute__((ext_vector_type(4))) float f32x4;
typedef __attribute__((ext_vector_type(2))) float f32x2;

struct WPtrs { const void* p[10]; };

__device__ inline float tanh_fast(float x) {
    float xc = fminf(fmaxf(x, -15.f), 15.f);
    float e  = __expf(2.f * xc);
    return 1.f - 2.f / (e + 1.f);
}
__device__ inline unsigned short f2bf(float f) {
    unsigned u = __float_as_uint(f);
    u += 0x7fff + ((u >> 16) & 1);
    return (unsigned short)(u >> 16);
}
__device__ inline float bf2f(unsigned short h) {
    return __uint_as_float(((unsigned)h) << 16);
}
__device__ inline int ld_idx(const void* p, long i, int imode) {
    return imode ? (int)((const long long*)p)[i] : ((const int*)p)[i];
}

// unpack one dword (2 bf16 feats) into a register-pair float2 -> feeds v_pk_add_f32
__device__ inline f32x2 unpk(unsigned v) {
    f32x2 r;
    r.x = __uint_as_float(v << 16);
    r.y = __uint_as_float(v & 0xffff0000u);
    return r;
}

// ================= setup kernels =================

__global__ void k_detect(const void* x, const void* eidx, int* modes) {
    int lane = threadIdx.x;
    const unsigned* xw = (const unsigned*)x;
    unsigned w = xw[lane];
    int ex = (w >> 7) & 0xFF;
    unsigned long long m = __ballot(ex >= 100 && ex <= 145);
    const unsigned* ew = (const unsigned*)eidx;
    unsigned long long m2 = __ballot(ew[2*lane + 1] != 0);
    if (lane == 0) {
        modes[0] = (__popcll(m) >= 48) ? 1 : 0;
        modes[1] = (__popcll(m2) == 0) ? 1 : 0;
    }
}

// merged: deg init + desc sentinel fill + h pad-row zeroing
__global__ void k_setup0(int* deg, unsigned* desc32, unsigned* hA32, unsigned* hB32) {
    int n = blockIdx.x * 256 + threadIdx.x;
    if (n < PITCH) deg[n] = (n < NNODE) ? 1 : 0;
    if (n < ECAP / 2) desc32[n] = 0x07FF07FFu;     // sentinel -> zero row 2047
    if (n < 2 * NG * 48 * 32) {
        int b = n / (NG * 48 * 32), r = n % (NG * 48 * 32);
        int g = r / (48 * 32), rr = r % (48 * 32);
        int row = NNODE + rr / 32, fp = rr % 32;
        unsigned* pp = b ? hB32 : hA32;
        pp[(g * PITCH + row) * 32 + fp] = 0;
    }
}

__global__ void k_count(const void* eidx, const int* __restrict__ modes, int* deg) {
    int e = blockIdx.x * 256 + threadIdx.x;
    int imode = modes[1];
    int dst = ld_idx(eidx, (long)EPG + e, imode);
    atomicAdd(&deg[dst], 1);
}

// pad rows to 8: padded slots read the zero row -> pure zero-adds;
// per-lane accumulation order (positions == p8 mod 8, increasing) unchanged.
__global__ __launch_bounds__(256) void k_scan(const int* __restrict__ deg, int* rowp,
                                              int* cursor, float* dinv) {
    __shared__ int part[256];
    int t = threadIdx.x, base = t * 8;
    int loc[8]; int s = 0;
    #pragma unroll
    for (int k = 0; k < 8; ++k) {
        int d = deg[base + k];
        int p = (d + 7) & ~7;
        loc[k] = p; s += p;
    }
    part[t] = s; __syncthreads();
    for (int off = 1; off < 256; off <<= 1) {
        int v = (t >= off) ? part[t - off] : 0;
        __syncthreads();
        part[t] += v;
        __syncthreads();
    }
    int run = part[t] - s;
    #pragma unroll
    for (int k = 0; k < 8; ++k) {
        rowp[base + k] = run; cursor[base + k] = run;
        int d = deg[base + k];
        dinv[base + k] = (d > 0) ? rsqrtf((float)d) : 0.f;
        run += loc[k];
    }
    if (t == 255) rowp[PITCH] = part[255];
}

__global__ void k_scatter(const void* eidx, const int* __restrict__ modes,
                          int* cursor, unsigned short* desc) {
    int idx = blockIdx.x * 256 + threadIdx.x;
    if (idx >= EPG + NNODE) return;
    int imode = modes[1];
    int s, d;
    if (idx < EPG) { s = ld_idx(eidx, idx, imode); d = ld_idx(eidx, (long)EPG + idx, imode); }
    else           { s = idx - EPG; d = s; }
    int pos = atomicAdd(&cursor[d], 1);
    desc[pos] = (unsigned short)s;
}

__global__ void k_convert(WPtrs wp, float* wf, const int* __restrict__ modes) {
    int idx = blockIdx.x * 256 + threadIdx.x;
    if (idx >= WFTOT) return;
    int fmode = modes[0];
    const int offs[10]  = {W0OFF,B0OFF,W1OFF,B1OFF,W2OFF,B2OFF,W3OFF,B3OFF,W4OFF,B4OFF};
    const int sizes[10] = {64,64,4096,64,4096,64,4096,64,64,1};
    #pragma unroll
    for (int s = 0; s < 10; ++s) {
        if (idx >= offs[s] && idx < offs[s] + sizes[s]) {
            int j = idx - offs[s];
            wf[idx] = fmode ? __bfloat162float(((const __hip_bfloat16*)wp.p[s])[j])
                            : ((const float*)wp.p[s])[j];
        }
    }
}

__global__ void k_mkfrag(const float* __restrict__ wf, short8* frag) {
    int t = blockIdx.x * 256 + threadIdx.x;
    if (t >= 3072) return;
    int lane = t & 63, half = (t >> 6) & 1, kh = (t >> 7) & 1, nb = (t >> 8) & 3, mat = t >> 10;
    const int woffs[3] = {W1OFF, W2OFF, W3OFF};
    const float* W = wf + woffs[mat];
    int n  = nb * 16 + (lane & 15);
    int k0 = kh * 32 + (lane >> 4) * 8;
    short8 v;
    #pragma unroll
    for (int j = 0; j < 8; ++j) {
        float w = W[(k0 + j) * 64 + n];
        unsigned short h = f2bf(w);
        v[j] = half ? (short)f2bf(w - bf2f(h)) : (short)h;
    }
    frag[t] = v;
}

__global__ void k_finalize(const float* __restrict__ dinv, const void* x,
                           const int* __restrict__ modes,
                           float* yin, float* yb, float* s4, void* out) {
    int idx = blockIdx.x * 256 + threadIdx.x;
    if (idx >= NG * PITCH) return;
    int g = idx >> 11, local = idx & (PITCH - 1);
    if (local >= NNODE) { yin[idx] = 0.f; yb[idx] = 0.f; s4[idx] = 0.f; return; }
    int cn = g * NNODE + local;
    float y0 = modes[0] ? __bfloat162float(((const __hip_bfloat16*)x)[cn * TSTEPS + (TSTEPS - 1)])
                        : ((const float*)x)[cn * TSTEPS + (TSTEPS - 1)];
    yin[idx] = dinv[local] * y0;
    yb[idx]  = y0;
    if (modes[0]) ((__hip_bfloat16*)out)[cn * HOR] = __float2bfloat16(y0);
    else          ((float*)out)[cn * HOR] = y0;
}

// ---- layer 0: 16 lanes per node, 4 nodes/wave, tile/block, grid 1000 ----
__global__ __launch_bounds__(256) void k_layer0(
        const float* __restrict__ yin, unsigned short* __restrict__ hout,
        const unsigned short* __restrict__ desc, const int* __restrict__ rowp,
        const float* __restrict__ dinv, const float* __restrict__ wf) {
    int lane = threadIdx.x & 63, wv = threadIdx.x >> 6;
    int b = blockIdx.x;
    int g = b & 7, tb = (b >> 3) << 4;
    const float* yg = yin + g * PITCH;
    int grp = lane >> 4, j = lane & 15;
    int local = tb + (wv << 2) + grp;
    int s = rowp[local], e = rowp[local + 1];
    float acc = 0.f;
    for (int i = s + j; i < e; i += 16) acc += yg[desc[i]];
    acc += __shfl_xor(acc, 1); acc += __shfl_xor(acc, 2);
    acc += __shfl_xor(acc, 4); acc += __shfl_xor(acc, 8);
    float w0 = wf[W0OFF + lane], b0 = wf[B0OFF + lane];
    #pragma unroll
    for (int r = 0; r < 4; ++r) {
        float Z = __shfl(acc, r << 4);
        int ln = tb + (wv << 2) + r;
        float dv = dinv[ln];
        float o = dv * tanh_fast(dv * Z * w0 + b0);
        hout[((size_t)(g * PITCH + ln) << 6) + lane] = f2bf(o);
    }
}

// ---- heavy gather: dwordx4 rows, 32-edge unroll + 16/8 tails, packed f32x2 acc.
// 8 waves/block, 2 rows per wave (was 4): halves the serial row chain per wave,
// ~31/32 waves/CU occupancy. Per-row lane mapping + accumulation order
// bit-identical to the proven version. ----
__device__ __forceinline__ void acc8(uint4 v, f32x2& a01, f32x2& a23,
                                     f32x2& a45, f32x2& a67) {
    a01 += unpk(v.x);
    a23 += unpk(v.y);
    a45 += unpk(v.z);
    a67 += unpk(v.w);
}

__device__ __forceinline__ void gather_tile2(
        const uint4* __restrict__ hg128, const unsigned short* __restrict__ desc,
        const int* __restrict__ rowp, const float* __restrict__ dinv,
        int tb, int lane, int wv, float* tile, float* dinvt) {
    int fp3 = lane & 7, p8 = lane >> 3;
    #pragma unroll
    for (int r = 0; r < 2; ++r) {
        int m = (wv << 1) + r;
        int local = tb + m;
        int s = rowp[local], e = rowp[local + 1];   // multiples of 8
        f32x2 a01 = {0.f, 0.f}, a23 = {0.f, 0.f}, a45 = {0.f, 0.f}, a67 = {0.f, 0.f};
        int i = s;
        for (; i + 32 <= e; i += 32) {
            unsigned e0 = desc[i + p8];
            unsigned e1 = desc[i + 8 + p8];
            unsigned e2 = desc[i + 16 + p8];
            unsigned e3 = desc[i + 24 + p8];
            uint4 v0 = hg128[(e0 << 3) + fp3];
            uint4 v1 = hg128[(e1 << 3) + fp3];
            uint4 v2 = hg128[(e2 << 3) + fp3];
            uint4 v3 = hg128[(e3 << 3) + fp3];
            acc8(v0, a01, a23, a45, a67);
            acc8(v1, a01, a23, a45, a67);
            acc8(v2, a01, a23, a45, a67);
            acc8(v3, a01, a23, a45, a67);
        }
        if (i + 16 <= e) {
            unsigned e0 = desc[i + p8];
            unsigned e1 = desc[i + 8 + p8];
            uint4 v0 = hg128[(e0 << 3) + fp3];
            uint4 v1 = hg128[(e1 << 3) + fp3];
            acc8(v0, a01, a23, a45, a67);
            acc8(v1, a01, a23, a45, a67);
            i += 16;
        }
        if (i < e) {                                // 8-edge tail (pad-8)
            unsigned e0 = desc[i + p8];
            uint4 v0 = hg128[(e0 << 3) + fp3];
            acc8(v0, a01, a23, a45, a67);
        }
        float dv = dinv[local];
        f32x2 dv2 = {dv, dv};
        a01 *= dv2; a23 *= dv2; a45 *= dv2; a67 *= dv2;
        float a0 = a01.x, a1 = a01.y, a2 = a23.x, a3 = a23.y;
        float a4 = a45.x, a5 = a45.y, a6 = a67.x, a7 = a67.y;
        a0 += __shfl_xor(a0, 8); a0 += __shfl_xor(a0, 16); a0 += __shfl_xor(a0, 32);
        a1 += __shfl_xor(a1, 8); a1 += __shfl_xor(a1, 16); a1 += __shfl_xor(a1, 32);
        a2 += __shfl_xor(a2, 8); a2 += __shfl_xor(a2, 16); a2 += __shfl_xor(a2, 32);
        a3 += __shfl_xor(a3, 8); a3 += __shfl_xor(a3, 16); a3 += __shfl_xor(a3, 32);
        a4 += __shfl_xor(a4, 8); a4 += __shfl_xor(a4, 16); a4 += __shfl_xor(a4, 32);
        a5 += __shfl_xor(a5, 8); a5 += __shfl_xor(a5, 16); a5 += __shfl_xor(a5, 32);
        a6 += __shfl_xor(a6, 8); a6 += __shfl_xor(a6, 16); a6 += __shfl_xor(a6, 32);
        a7 += __shfl_xor(a7, 8); a7 += __shfl_xor(a7, 16); a7 += __shfl_xor(a7, 32);
        if (p8 == 0) {
            float4* dst = (float4*)&tile[m * 68 + (fp3 << 3)];
            dst[0] = make_float4(a0, a1, a2, a3);
            dst[1] = make_float4(a4, a5, a6, a7);
        }
        if (lane == 0) dinvt[m] = dv;
    }
}

__device__ __forceinline__ f32x4 transform_tile(
        const float* tile, const short8* __restrict__ fb,
        const float* __restrict__ wf, int boff, int lane, int wv) {
    short8 Bh0 = fb[(wv << 8) +   0 + lane];
    short8 Bl0 = fb[(wv << 8) +  64 + lane];
    short8 Bh1 = fb[(wv << 8) + 128 + lane];
    short8 Bl1 = fb[(wv << 8) + 192 + lane];
    int mrow = lane & 15, quad = lane >> 4;
    const float* arow = &tile[mrow * 68];
    float4 a0 = *(const float4*)(arow + (quad << 3));
    float4 a1 = *(const float4*)(arow + (quad << 3) + 4);
    float4 a2 = *(const float4*)(arow + 32 + (quad << 3));
    float4 a3 = *(const float4*)(arow + 32 + (quad << 3) + 4);
    float av0[8] = {a0.x, a0.y, a0.z, a0.w, a1.x, a1.y, a1.z, a1.w};
    float av1[8] = {a2.x, a2.y, a2.z, a2.w, a3.x, a3.y, a3.z, a3.w};
    short8 Ah0, Al0, Ah1, Al1;
    #pragma unroll
    for (int j = 0; j < 8; ++j) {
        unsigned short h0 = f2bf(av0[j]);
        Ah0[j] = (short)h0; Al0[j] = (short)f2bf(av0[j] - bf2f(h0));
        unsigned short h1 = f2bf(av1[j]);
        Ah1[j] = (short)h1; Al1[j] = (short)f2bf(av1[j] - bf2f(h1));
    }
    float bias = wf[boff + (wv << 4) + mrow];
    f32x4 c = {bias, bias, bias, bias};
    c = __builtin_amdgcn_mfma_f32_16x16x32_bf16(Ah0, Bh0, c, 0, 0, 0);
    c = __builtin_amdgcn_mfma_f32_16x16x32_bf16(Al0, Bh0, c, 0, 0, 0);
    c = __builtin_amdgcn_mfma_f32_16x16x32_bf16(Ah0, Bl0, c, 0, 0, 0);
    c = __builtin_amdgcn_mfma_f32_16x16x32_bf16(Ah1, Bh1, c, 0, 0, 0);
    c = __builtin_amdgcn_mfma_f32_16x16x32_bf16(Al1, Bh1, c, 0, 0, 0);
    c = __builtin_amdgcn_mfma_f32_16x16x32_bf16(Ah1, Bl1, c, 0, 0, 0);
    return c;
}

// ---- heavy layers: 512 threads (8 waves); waves 0-3 own the MFMA transform ----
template<int FUSE>
__global__ __launch_bounds__(512, 4) void k_layer(
        const unsigned short* __restrict__ hin, unsigned short* __restrict__ hout,
        float* __restrict__ s4,
        const unsigned short* __restrict__ desc, const int* __restrict__ rowp,
        const float* __restrict__ dinv, const float* __restrict__ wf,
        const short8* __restrict__ frag, int mat, int boff) {
    __shared__ float tile[16 * 68];
    __shared__ float dinvt[16];
    __shared__ float pd[4][16];
    int lane = threadIdx.x & 63, wv = threadIdx.x >> 6;   // wv 0..7
    int b = blockIdx.x;
    int g = b & 7, tb = (b >> 3) << 4;
    const uint4* hg128 = (const uint4*)(hin + ((size_t)g * PITCH << 6));

    gather_tile2(hg128, desc, rowp, dinv, tb, lane, wv, tile, dinvt);
    __syncthreads();

    if (!FUSE) {
        if (wv < 4) {
            f32x4 c = transform_tile(tile, frag + (mat << 10), wf, boff, lane, wv);
            int mrow = lane & 15, quad = lane >> 4;
            #pragma unroll
            for (int r = 0; r < 4; ++r) {
                int m = (quad << 2) + r;
                hout[(((size_t)g * PITCH + tb + m) << 6) + (wv << 4) + mrow] =
                    f2bf(dinvt[m] * tanh_fast(c[r]));
            }
        }
    } else {
        if (wv < 4) {
            f32x4 c = transform_tile(tile, frag + (mat << 10), wf, boff, lane, wv);
            int mrow = lane & 15, quad = lane >> 4;
            float w4v = wf[W4OFF + (wv << 4) + mrow];
            #pragma unroll
            for (int r = 0; r < 4; ++r) {
                float d = tanh_fast(c[r]) * w4v;
                d += __shfl_xor(d, 1); d += __shfl_xor(d, 2);
                d += __shfl_xor(d, 4); d += __shfl_xor(d, 8);
                if (mrow == 0) pd[wv][(quad << 2) + r] = d;
            }
        }
        __syncthreads();
        if (threadIdx.x < 16)
            s4[g * PITCH + tb + threadIdx.x] = dinvt[threadIdx.x] *
                (pd[0][threadIdx.x] + pd[1][threadIdx.x] + pd[2][threadIdx.x] + pd[3][threadIdx.x]);
    }
}

// ---- prop: 16 lanes per node, 4 nodes/wave, grid 1000 ----
__global__ __launch_bounds__(256) void k_prop(
        const float* __restrict__ s4, const unsigned short* __restrict__ desc,
        const int* __restrict__ rowp, const float* __restrict__ dinv,
        const float* __restrict__ wf,
        float* yin, float* yb, float* kA, float* kB, float* kC,
        float c1, float c2, float c3, float c4, int stage,
        const int* __restrict__ modes, void* out, int hidx) {
    int lane = threadIdx.x & 63, wv = threadIdx.x >> 6;
    int b = blockIdx.x;
    int g = b & 7, tb = (b >> 3) << 4;
    const float* sg = s4 + g * PITCH;
    int grp = lane >> 4, j = lane & 15;
    int local = tb + (wv << 2) + grp;
    int s = rowp[local], e = rowp[local + 1];
    float acc = 0.f;
    for (int i = s + j; i < e; i += 16) acc += sg[desc[i]];
    acc += __shfl_xor(acc, 1); acc += __shfl_xor(acc, 2);
    acc += __shfl_xor(acc, 4); acc += __shfl_xor(acc, 8);
    if (j == 0) {
        int idx = g * PITCH + local;
        float dv = dinv[local];
        float k = dv * acc + wf[B4OFF];
        float ynew = yb[idx] + c1 * kA[idx] + c2 * kB[idx] + c3 * kC[idx] + c4 * k;
        if (stage == 0) kA[idx] = k;
        else if (stage == 1) kB[idx] = k;
        else if (stage == 2) kC[idx] = k;
        yin[idx] = dv * ynew;
        if (stage == 3) {
            yb[idx] = ynew;
            int cn = g * NNODE + local;
            if (modes[0]) ((__hip_bfloat16*)out)[cn * HOR + hidx] = __float2bfloat16(ynew);
            else          ((float*)out)[cn * HOR + hidx] = ynew;
        }
    }
}

// ================= host =================

extern "C" void kernel_launch(void* const* d_in, const int* in_sizes, int n_in,
                              void* d_out, int out_size, void* d_ws, size_t ws_size,
                              hipStream_t stream) {
    char* ws = (char*)d_ws;
    unsigned short* desc = (unsigned short*)(ws + OFF_DESC);
    unsigned short* hA   = (unsigned short*)(ws + OFF_HA);
    unsigned short* hB   = (unsigned short*)(ws + OFF_HB);
    float* yin  = (float*)(ws + OFF_YIN);
    float* yb   = (float*)(ws + OFF_YB);
    float* kA   = (float*)(ws + OFF_KA);
    float* kB   = (float*)(ws + OFF_KB);
    float* kC   = (float*)(ws + OFF_KC);
    float* s4   = (float*)(ws + OFF_S4);
    int*   deg  = (int*)(ws + OFF_DEG);
    int*   cur  = (int*)(ws + OFF_CUR);
    int*   rowp = (int*)(ws + OFF_ROWP);
    float* dinv = (float*)(ws + OFF_DINV);
    int*   modes= (int*)(ws + OFF_MODES);
    float* wf   = (float*)(ws + OFF_WF);
    short8* wfrag = (short8*)(ws + OFF_WFRAG);

    const void* x    = d_in[0];
    const void* eidx = d_in[1];
    WPtrs wp;
    for (int i = 0; i < 10; ++i) wp.p[i] = d_in[2 + i];

    k_detect  <<<1, 64, 0, stream>>>(x, eidx, modes);
    k_setup0  <<<192, 256, 0, stream>>>(deg, (unsigned*)desc, (unsigned*)hA, (unsigned*)hB);
    k_count   <<<EPG / 256, 256, 0, stream>>>(eidx, modes, deg);
    k_scan    <<<1, 256, 0, stream>>>(deg, rowp, cur, dinv);
    k_scatter <<<(EPG + NNODE + 255) / 256, 256, 0, stream>>>(eidx, modes, cur, desc);
    k_convert <<<(WFTOT + 255) / 256, 256, 0, stream>>>(wp, wf, modes);
    k_mkfrag  <<<12, 256, 0, stream>>>(wf, wfrag);
    k_finalize<<<NG * PITCH / 256, 256, 0, stream>>>(dinv, x, modes, yin, yb, s4, d_out);

    const float dt = 10.f / 9.f, dt3 = dt / 3.f;
    const float C1[4] = {0.f,  -dt3, dt,  dt * 0.125f};
    const float C2[4] = {0.f,  0.f,  -dt, dt * 0.375f};
    const float C3[4] = {0.f,  0.f,  0.f, dt * 0.375f};
    const float C4[4] = {dt3,  dt,   dt,  dt * 0.125f};

    k_layer0<<<1000, 256, 0, stream>>>(yin, hA, desc, rowp, dinv, wf);  // initial

    for (int step = 0; step < NSTEP; ++step) {
        for (int st = 0; st < 4; ++st) {
            k_layer<0><<<1000, 512, 0, stream>>>(hA, hB, nullptr, desc, rowp, dinv, wf, wfrag, 0, B1OFF);
            k_layer<0><<<1000, 512, 0, stream>>>(hB, hA, nullptr, desc, rowp, dinv, wf, wfrag, 1, B2OFF);
            k_layer<1><<<1000, 512, 0, stream>>>(hA, nullptr, s4, desc, rowp, dinv, wf, wfrag, 2, B3OFF);
            k_prop    <<<1000, 256, 0, stream>>>(s4, desc, rowp, dinv, wf, yin, yb, kA, kB, kC,
                                                 C1[st], C2[st], C3[st], C4[st], st,
                                                 modes, d_out, step + 1);
            if (step < NSTEP - 1 || st < 3)
                k_layer0<<<1000, 256, 0, stream>>>(yin, hA, desc, rowp, dinv, wf);
        }
    }
}